// Round 1
// baseline (5141.713 us; speedup 1.0000x reference)
//
#include <hip/hip_runtime.h>
#include <math.h>

// Problem constants
#define B_ 4
#define T_ 256
#define N_ 8
#define D_ 128
#define NH_ 4
#define HD_ 32
#define LENC_ 2
#define MLPH_ 32
#define NL_SCALE_ 0.1f
#define QB 4       // queries per attention block
#define MAXLK 2048

__device__ __forceinline__ float gelu_f(float x) {
    return 0.5f * x * (1.0f + erff(x * 0.7071067811865476f));
}

// Power-of-2 blockDim tree reduction. All threads must call.
__device__ __forceinline__ float block_sum(float v, float* scratch) {
    int tid = threadIdx.x;
    scratch[tid] = v;
    __syncthreads();
    for (int s = blockDim.x >> 1; s > 0; s >>= 1) {
        if (tid < s) scratch[tid] += scratch[tid + s];
        __syncthreads();
    }
    float r = scratch[0];
    __syncthreads();
    return r;
}

__device__ __forceinline__ float block_max(float v, float* scratch) {
    int tid = threadIdx.x;
    scratch[tid] = v;
    __syncthreads();
    for (int s = blockDim.x >> 1; s > 0; s >>= 1) {
        if (tid < s) scratch[tid] = fmaxf(scratch[tid], scratch[tid + s]);
        __syncthreads();
    }
    float r = scratch[0];
    __syncthreads();
    return r;
}

// ---------------------------------------------------------------------------
// K1: b1[b,t,m] = r5[m] + sum_n x*A55[m,n] + 0.1*nl + bl_bias[m], t in [0,T-1)
__global__ void k_b1(const float* __restrict__ vs, const float* __restrict__ r5,
                     const float* __restrict__ A55, const float* __restrict__ bl_bias,
                     const float* __restrict__ nlW1, const float* __restrict__ nlb1,
                     const float* __restrict__ nlW2, const float* __restrict__ nlb2,
                     float* __restrict__ b1w) {
    int idx = blockIdx.x * blockDim.x + threadIdx.x;
    if (idx >= B_ * (T_ - 1)) return;
    int b = idx / (T_ - 1), t = idx % (T_ - 1);
    float x[N_];
    for (int n = 0; n < N_; n++) x[n] = vs[(b * T_ + t) * N_ + n];
    float h[MLPH_];
    for (int j = 0; j < MLPH_; j++) {
        float a = nlb1[j];
        for (int n = 0; n < N_; n++) a += x[n] * nlW1[j * N_ + n];
        h[j] = gelu_f(a);
    }
    for (int m = 0; m < N_; m++) {
        float lin = r5[m];
        for (int n = 0; n < N_; n++) lin += x[n] * A55[m * N_ + n];
        float nl = nlb2[m];
        for (int j = 0; j < MLPH_; j++) nl += h[j] * nlW2[m * MLPH_ + j];
        b1w[idx * N_ + m] = lin + NL_SCALE_ * nl + bl_bias[m];
    }
}

// ---------------------------------------------------------------------------
// K2: residuals[b,t,n,si] for SCALES = {1,2,3,5}
__global__ void k_resid(const float* __restrict__ vs, const float* __restrict__ b1w,
                        float* __restrict__ resid) {
    int idx = blockIdx.x * blockDim.x + threadIdx.x;
    if (idx >= B_ * T_ * N_) return;
    int b = idx / (T_ * N_);
    int t = (idx / N_) % T_;
    int n = idx % N_;
    const int SC[4] = {1, 2, 3, 5};
    float lx0 = logf(fmaxf(vs[(b * T_ + t) * N_ + n], 1e-6f));
    for (int si = 0; si < 4; si++) {
        int k = SC[si];
        float r = 0.0f;
        if (t < T_ - k) {
            float lx1 = logf(fmaxf(vs[(b * T_ + t + k) * N_ + n], 1e-6f));
            float a = lx1 - lx0;
            float cmin = -2.5f * (float)k, cmax = 2.0f * (float)k;
            a = fminf(fmaxf(a, cmin), cmax);
            float bk = 0.0f;
            for (int i = 0; i < k; i++) bk += b1w[(b * (T_ - 1) + t + i) * N_ + n];
            r = a - bk;
        }
        resid[idx * 4 + si] = r;
    }
}

// ---------------------------------------------------------------------------
// K3: per-token MLP 16->128->128 + LN + PE, write transposed xt[(b*N+n)*T+t][d]
__global__ void k_mlp(const float* __restrict__ resid, const float* __restrict__ W1,
                      const float* __restrict__ b1, const float* __restrict__ W2,
                      const float* __restrict__ b2, const float* __restrict__ g,
                      const float* __restrict__ be, float* __restrict__ xt) {
    int tok = blockIdx.x;                 // over B*T*N
    int b = tok / (T_ * N_);
    int t = (tok / N_) % T_;
    int n = tok % N_;
    int d = threadIdx.x;                  // 128
    __shared__ float f[16];
    __shared__ float h1[D_];
    __shared__ float scratch[D_];
    if (d < 16) {
        int lag = d >> 2;                 // group 0..3 -> lag 0,1,2,3
        int si = d & 3;
        f[d] = (t - lag >= 0) ? resid[((b * T_ + (t - lag)) * N_ + n) * 4 + si] : 0.0f;
    }
    __syncthreads();
    float a = b1[d];
    const float* w1r = W1 + d * 16;
    for (int c = 0; c < 16; c++) a += f[c] * w1r[c];
    h1[d] = gelu_f(a);
    __syncthreads();
    float a2 = b2[d];
    const float4* w2r = (const float4*)(W2 + d * D_);
    const float4* h14 = (const float4*)h1;
    for (int j = 0; j < D_ / 4; j++) {
        float4 w = w2r[j]; float4 x = h14[j];
        a2 += w.x * x.x + w.y * x.y + w.z * x.z + w.w * x.w;
    }
    float v = gelu_f(a2);
    float mean = block_sum(v, scratch) * (1.0f / D_);
    float dv = v - mean;
    float var = block_sum(dv * dv, scratch) * (1.0f / D_);
    float y = dv * rsqrtf(var + 1e-5f) * g[d] + be[d];
    // positional encoding
    int j = d >> 1;
    float freq = expf((float)(2 * j) * (-logf(10000.0f) / (float)D_));
    float ang = (float)t * freq;
    y += (d & 1) ? cosf(ang) : sinf(ang);
    xt[((b * N_ + n) * T_ + t) * D_ + d] = y;
}

// ---------------------------------------------------------------------------
// K4: encoder QKV projection. block = token (s*T+t), 384 threads.
__global__ void k_qkv_enc(const float* __restrict__ xt, const float* __restrict__ W,
                          const float* __restrict__ bias, float* __restrict__ Qb,
                          float* __restrict__ Kb, float* __restrict__ Vb) {
    int tok = blockIdx.x;                 // s*T + t
    int s = tok / T_, t = tok % T_;
    int tid = threadIdx.x;                // 0..383
    __shared__ float xv[D_];
    if (tid < D_) xv[tid] = xt[tok * D_ + tid];
    __syncthreads();
    float a = bias[tid];
    const float4* wr = (const float4*)(W + (size_t)tid * D_);
    const float4* xv4 = (const float4*)xv;
    for (int j = 0; j < D_ / 4; j++) {
        float4 w = wr[j]; float4 x = xv4[j];
        a += w.x * x.x + w.y * x.y + w.z * x.z + w.w * x.w;
    }
    int which = tid >> 7;                 // 0=Q 1=K 2=V
    int o = tid & 127;
    int h = o >> 5, dd = o & 31;
    float* dst = (which == 0) ? Qb : (which == 1) ? Kb : Vb;
    dst[((s * NH_ + h) * T_ + t) * HD_ + dd] = a;
}

// ---------------------------------------------------------------------------
// K5: cross QKV. Q from state_emb token, K/V from encoder output (remapped).
__global__ void k_qkv_cross(const float* __restrict__ semb, const float* __restrict__ xt,
                            const float* __restrict__ Wq, const float* __restrict__ bq,
                            const float* __restrict__ Wk, const float* __restrict__ bk,
                            const float* __restrict__ Wv, const float* __restrict__ bv,
                            float* __restrict__ Qb, float* __restrict__ Kb,
                            float* __restrict__ Vb) {
    int tok = blockIdx.x;                 // b*2048 + l
    int b = tok >> 11;
    int l = tok & 2047;
    int t = l >> 3, n = l & 7;
    int tid = threadIdx.x;                // 0..383
    __shared__ float sv[D_], rv[D_];
    if (tid < D_) {
        sv[tid] = semb[(size_t)tok * D_ + tid];
        rv[tid] = xt[((b * N_ + n) * T_ + t) * D_ + tid];
    }
    __syncthreads();
    int which = tid >> 7;
    int o = tid & 127;
    const float* W = (which == 0) ? Wq : (which == 1) ? Wk : Wv;
    const float* bb = (which == 0) ? bq : (which == 1) ? bk : bv;
    const float* src = (which == 0) ? sv : rv;
    float a = bb[o];
    const float4* wr = (const float4*)(W + (size_t)o * D_);
    const float4* s4 = (const float4*)src;
    for (int j = 0; j < D_ / 4; j++) {
        float4 w = wr[j]; float4 x = s4[j];
        a += w.x * x.x + w.y * x.y + w.z * x.z + w.w * x.w;
    }
    int h = o >> 5, dd = o & 31;
    float* dst = (which == 0) ? Qb : (which == 1) ? Kb : Vb;
    dst[((b * NH_ + h) * 2048 + l) * HD_ + dd] = a;
}

// ---------------------------------------------------------------------------
// K6: attention. block handles QB queries of one (seq,head). 256 threads.
__global__ __launch_bounds__(256) void k_attn(const float* __restrict__ Qb,
                                              const float* __restrict__ Kb,
                                              const float* __restrict__ Vb,
                                              float* __restrict__ att, int Lq, int Lk) {
    __shared__ float sc[QB][MAXLK];
    __shared__ float qv[QB][HD_];
    __shared__ float scratch[256];
    __shared__ float part[8][HD_][QB];
    __shared__ float sbuf[QB];
    int nqb = Lq / QB;
    int bid = blockIdx.x;
    int qb = bid % nqb;
    int h = (bid / nqb) % NH_;
    int s = bid / (nqb * NH_);
    int tid = threadIdx.x;
    const float* Qp = Qb + ((size_t)(s * NH_ + h) * Lq + qb * QB) * HD_;
    const float* Kp = Kb + (size_t)(s * NH_ + h) * Lk * HD_;
    const float* Vp = Vb + (size_t)(s * NH_ + h) * Lk * HD_;
    if (tid < QB * HD_) qv[tid >> 5][tid & 31] = Qp[tid];
    __syncthreads();
    const float scale = 0.17677669529663687f;  // 1/sqrt(32)
    for (int k = tid; k < Lk; k += 256) {
        const float4* kp4 = (const float4*)(Kp + (size_t)k * HD_);
        float a0 = 0, a1 = 0, a2 = 0, a3 = 0;
#pragma unroll
        for (int d4 = 0; d4 < 8; d4++) {
            float4 kv = kp4[d4];
            int d0 = d4 * 4;
            a0 += qv[0][d0] * kv.x + qv[0][d0 + 1] * kv.y + qv[0][d0 + 2] * kv.z + qv[0][d0 + 3] * kv.w;
            a1 += qv[1][d0] * kv.x + qv[1][d0 + 1] * kv.y + qv[1][d0 + 2] * kv.z + qv[1][d0 + 3] * kv.w;
            a2 += qv[2][d0] * kv.x + qv[2][d0 + 1] * kv.y + qv[2][d0 + 2] * kv.z + qv[2][d0 + 3] * kv.w;
            a3 += qv[3][d0] * kv.x + qv[3][d0 + 1] * kv.y + qv[3][d0 + 2] * kv.z + qv[3][d0 + 3] * kv.w;
        }
        sc[0][k] = a0 * scale; sc[1][k] = a1 * scale;
        sc[2][k] = a2 * scale; sc[3][k] = a3 * scale;
    }
    __syncthreads();
    for (int qi = 0; qi < QB; qi++) {
        float m = -1e30f;
        for (int k = tid; k < Lk; k += 256) m = fmaxf(m, sc[qi][k]);
        m = block_max(m, scratch);
        float sum = 0.0f;
        for (int k = tid; k < Lk; k += 256) {
            float e = expf(sc[qi][k] - m);
            sc[qi][k] = e;
            sum += e;
        }
        sum = block_sum(sum, scratch);
        if (tid == 0) sbuf[qi] = 1.0f / sum;
    }
    __syncthreads();
    // PV: thread (chunk, d); 8 chunks x 32 dims
    int d = tid & 31, chunk = tid >> 5;
    float acc[QB] = {0, 0, 0, 0};
    for (int k = chunk; k < Lk; k += 8) {
        float vv = Vp[(size_t)k * HD_ + d];
        acc[0] += sc[0][k] * vv; acc[1] += sc[1][k] * vv;
        acc[2] += sc[2][k] * vv; acc[3] += sc[3][k] * vv;
    }
#pragma unroll
    for (int qi = 0; qi < QB; qi++) part[chunk][d][qi] = acc[qi];
    __syncthreads();
    if (tid < QB * HD_) {
        int qi = tid >> 5, d2 = tid & 31;
        float a = 0;
#pragma unroll
        for (int c = 0; c < 8; c++) a += part[c][d2][qi];
        int q = qb * QB + qi;
        att[((size_t)s * Lq + q) * D_ + h * HD_ + d2] = a * sbuf[qi];
    }
}

// ---------------------------------------------------------------------------
// K7: out-projection + residual + LN. block = token, 128 threads.
__global__ void k_outproj_ln(const float* __restrict__ att, const float* __restrict__ Wo,
                             const float* __restrict__ bo, const float* __restrict__ xin,
                             const float* __restrict__ g, const float* __restrict__ be,
                             float* __restrict__ xout) {
    int tok = blockIdx.x;
    int d = threadIdx.x;
    __shared__ float av[D_];
    __shared__ float scratch[D_];
    av[d] = att[(size_t)tok * D_ + d];
    __syncthreads();
    float a = bo[d];
    const float4* wr = (const float4*)(Wo + (size_t)d * D_);
    const float4* av4 = (const float4*)av;
    for (int j = 0; j < D_ / 4; j++) {
        float4 w = wr[j]; float4 x = av4[j];
        a += w.x * x.x + w.y * x.y + w.z * x.z + w.w * x.w;
    }
    float v = xin[(size_t)tok * D_ + d] + a;
    float mean = block_sum(v, scratch) * (1.0f / D_);
    float dv = v - mean;
    float var = block_sum(dv * dv, scratch) * (1.0f / D_);
    xout[(size_t)tok * D_ + d] = dv * rsqrtf(var + 1e-5f) * g[d] + be[d];
}

// ---------------------------------------------------------------------------
// K8: encoder FF 128->256->128 + residual + LN. block = token, 256 threads.
__global__ void k_ff_enc(const float* __restrict__ xin, const float* __restrict__ W1,
                         const float* __restrict__ b1, const float* __restrict__ W2,
                         const float* __restrict__ b2, const float* __restrict__ g,
                         const float* __restrict__ be, float* __restrict__ xout) {
    int tok = blockIdx.x;
    int tid = threadIdx.x;                // 0..255
    __shared__ float xv[D_];
    __shared__ float h[256];
    __shared__ float scratch[256];
    if (tid < D_) xv[tid] = xin[(size_t)tok * D_ + tid];
    __syncthreads();
    float a = b1[tid];
    const float4* wr = (const float4*)(W1 + (size_t)tid * D_);
    const float4* xv4 = (const float4*)xv;
    for (int j = 0; j < D_ / 4; j++) {
        float4 w = wr[j]; float4 x = xv4[j];
        a += w.x * x.x + w.y * x.y + w.z * x.z + w.w * x.w;
    }
    h[tid] = gelu_f(a);
    __syncthreads();
    float v = 0.0f;
    if (tid < D_) {
        float a2 = b2[tid];
        const float4* w2 = (const float4*)(W2 + (size_t)tid * 256);
        const float4* h4 = (const float4*)h;
        for (int j = 0; j < 256 / 4; j++) {
            float4 w = w2[j]; float4 x = h4[j];
            a2 += w.x * x.x + w.y * x.y + w.z * x.z + w.w * x.w;
        }
        v = xv[tid] + a2;
    }
    float mean = block_sum(v, scratch) * (1.0f / D_);
    float dv = (tid < D_) ? (v - mean) : 0.0f;
    float var = block_sum(dv * dv, scratch) * (1.0f / D_);
    if (tid < D_)
        xout[(size_t)tok * D_ + tid] = dv * rsqrtf(var + 1e-5f) * g[tid] + be[tid];
}

// ---------------------------------------------------------------------------
// K9: cross fused FF: concat([s1, r]) 256 -> 512 -> 128, +s1, LN. 512 threads.
__global__ void k_ff_cross(const float* __restrict__ S1, const float* __restrict__ xt,
                           const float* __restrict__ W1, const float* __restrict__ b1,
                           const float* __restrict__ W2, const float* __restrict__ b2,
                           const float* __restrict__ g, const float* __restrict__ be,
                           float* __restrict__ out) {
    int tok = blockIdx.x;                 // b*2048 + l
    int b = tok >> 11;
    int l = tok & 2047;
    int t = l >> 3, n = l & 7;
    int tid = threadIdx.x;                // 0..511
    __shared__ float cat[256];
    __shared__ float h[512];
    __shared__ float scratch[512];
    if (tid < D_) cat[tid] = S1[(size_t)tok * D_ + tid];
    else if (tid < 256) cat[tid] = xt[((b * N_ + n) * T_ + t) * D_ + (tid - D_)];
    __syncthreads();
    float a = b1[tid];
    const float4* wr = (const float4*)(W1 + (size_t)tid * 256);
    const float4* c4 = (const float4*)cat;
    for (int j = 0; j < 256 / 4; j++) {
        float4 w = wr[j]; float4 x = c4[j];
        a += w.x * x.x + w.y * x.y + w.z * x.z + w.w * x.w;
    }
    h[tid] = gelu_f(a);
    __syncthreads();
    float v = 0.0f;
    if (tid < D_) {
        float a2 = b2[tid];
        const float4* w2 = (const float4*)(W2 + (size_t)tid * 512);
        const float4* h4 = (const float4*)h;
        for (int j = 0; j < 512 / 4; j++) {
            float4 w = w2[j]; float4 x = h4[j];
            a2 += w.x * x.x + w.y * x.y + w.z * x.z + w.w * x.w;
        }
        v = cat[tid] + a2;                // s1 + fused
    }
    float mean = block_sum(v, scratch) * (1.0f / D_);
    float dv = (tid < D_) ? (v - mean) : 0.0f;
    float var = block_sum(dv * dv, scratch) * (1.0f / D_);
    if (tid < D_)
        out[(size_t)tok * D_ + tid] = dv * rsqrtf(var + 1e-5f) * g[tid] + be[tid];
}

// ---------------------------------------------------------------------------
extern "C" void kernel_launch(void* const* d_in, const int* in_sizes, int n_in,
                              void* d_out, int out_size, void* d_ws, size_t ws_size,
                              hipStream_t stream) {
    const float* vs       = (const float*)d_in[0];
    const float* semb     = (const float*)d_in[1];
    const float* r5       = (const float*)d_in[2];
    const float* A55      = (const float*)d_in[3];
    const float* bl_bias  = (const float*)d_in[4];
    const float* nl_W1    = (const float*)d_in[5];
    const float* nl_b1    = (const float*)d_in[6];
    const float* nl_W2    = (const float*)d_in[7];
    const float* nl_b2    = (const float*)d_in[8];
    const float* mlp_W1   = (const float*)d_in[9];
    const float* mlp_b1   = (const float*)d_in[10];
    const float* mlp_W2   = (const float*)d_in[11];
    const float* mlp_b2   = (const float*)d_in[12];
    const float* mlp_ln_g = (const float*)d_in[13];
    const float* mlp_ln_b = (const float*)d_in[14];
    const float* enc_qkv_W = (const float*)d_in[15];
    const float* enc_qkv_b = (const float*)d_in[16];
    const float* enc_out_W = (const float*)d_in[17];
    const float* enc_out_b = (const float*)d_in[18];
    const float* enc_ln1_g = (const float*)d_in[19];
    const float* enc_ln1_b = (const float*)d_in[20];
    const float* enc_ff_W1 = (const float*)d_in[21];
    const float* enc_ff_b1 = (const float*)d_in[22];
    const float* enc_ff_W2 = (const float*)d_in[23];
    const float* enc_ff_b2 = (const float*)d_in[24];
    const float* enc_ln2_g = (const float*)d_in[25];
    const float* enc_ln2_b = (const float*)d_in[26];
    const float* ca_Wq = (const float*)d_in[27];
    const float* ca_bq = (const float*)d_in[28];
    const float* ca_Wk = (const float*)d_in[29];
    const float* ca_bk = (const float*)d_in[30];
    const float* ca_Wv = (const float*)d_in[31];
    const float* ca_bv = (const float*)d_in[32];
    const float* ca_Wo = (const float*)d_in[33];
    const float* ca_bo = (const float*)d_in[34];
    const float* ca_ln1_g = (const float*)d_in[35];
    const float* ca_ln1_b = (const float*)d_in[36];
    const float* ca_ff_W1 = (const float*)d_in[37];
    const float* ca_ff_b1 = (const float*)d_in[38];
    const float* ca_ff_W2 = (const float*)d_in[39];
    const float* ca_ff_b2 = (const float*)d_in[40];
    const float* ca_ln2_g = (const float*)d_in[41];
    const float* ca_ln2_b = (const float*)d_in[42];
    float* out = (float*)d_out;

    // Workspace layout (floats)
    float* ws = (float*)d_ws;
    float* b1w   = ws;                        // 8192
    float* resid = ws + 8192;                 // 32768
    float* X0    = ws + 8192 + 32768;         // 1048576
    float* X1    = X0 + 1048576;
    float* Qbuf  = X1 + 1048576;
    float* Kbuf  = Qbuf + 1048576;
    float* Vbuf  = Kbuf + 1048576;
    float* ATT   = Vbuf + 1048576;
    // total = 6,332,416 floats ≈ 25.3 MB

    const int NTOK = B_ * T_ * N_;            // 8192

    k_b1<<<dim3((B_ * (T_ - 1) + 63) / 64), dim3(64), 0, stream>>>(
        vs, r5, A55, bl_bias, nl_W1, nl_b1, nl_W2, nl_b2, b1w);

    k_resid<<<dim3(NTOK / 64), dim3(64), 0, stream>>>(vs, b1w, resid);

    k_mlp<<<dim3(NTOK), dim3(128), 0, stream>>>(
        resid, mlp_W1, mlp_b1, mlp_W2, mlp_b2, mlp_ln_g, mlp_ln_b, X0);

    // Encoder layers
    for (int i = 0; i < LENC_; i++) {
        const float* qkvW = enc_qkv_W + (size_t)i * 384 * 128;
        const float* qkvB = enc_qkv_b + (size_t)i * 384;
        k_qkv_enc<<<dim3(NTOK), dim3(384), 0, stream>>>(X0, qkvW, qkvB, Qbuf, Kbuf, Vbuf);
        k_attn<<<dim3(32 * NH_ * (T_ / QB)), dim3(256), 0, stream>>>(
            Qbuf, Kbuf, Vbuf, ATT, T_, T_);
        k_outproj_ln<<<dim3(NTOK), dim3(128), 0, stream>>>(
            ATT, enc_out_W + (size_t)i * 128 * 128, enc_out_b + (size_t)i * 128, X0,
            enc_ln1_g + (size_t)i * 128, enc_ln1_b + (size_t)i * 128, X1);
        k_ff_enc<<<dim3(NTOK), dim3(256), 0, stream>>>(
            X1, enc_ff_W1 + (size_t)i * 256 * 128, enc_ff_b1 + (size_t)i * 256,
            enc_ff_W2 + (size_t)i * 128 * 256, enc_ff_b2 + (size_t)i * 128,
            enc_ln2_g + (size_t)i * 128, enc_ln2_b + (size_t)i * 128, X0);
    }

    // Cross-attention: Q from state_emb, K/V from encoder output (X0)
    k_qkv_cross<<<dim3(NTOK), dim3(384), 0, stream>>>(
        semb, X0, ca_Wq, ca_bq, ca_Wk, ca_bk, ca_Wv, ca_bv, Qbuf, Kbuf, Vbuf);
    k_attn<<<dim3(B_ * NH_ * (2048 / QB)), dim3(256), 0, stream>>>(
        Qbuf, Kbuf, Vbuf, ATT, 2048, 2048);
    k_outproj_ln<<<dim3(NTOK), dim3(128), 0, stream>>>(
        ATT, ca_Wo, ca_bo, semb, ca_ln1_g, ca_ln1_b, X1);  // X1 = s1
    k_ff_cross<<<dim3(NTOK), dim3(512), 0, stream>>>(
        X1, X0, ca_ff_W1, ca_ff_b1, ca_ff_W2, ca_ff_b2, ca_ln2_g, ca_ln2_b, out);
}

// Round 2
// 2514.506 us; speedup vs baseline: 2.0448x; 2.0448x over previous
//
#include <hip/hip_runtime.h>
#include <math.h>

// Problem constants
#define B_ 4
#define T_ 256
#define N_ 8
#define D_ 128
#define NH_ 4
#define HD_ 32
#define LENC_ 2
#define MLPH_ 32
#define NL_SCALE_ 0.1f
#define TK2 32      // keys per LDS tile in flash attention

__device__ __forceinline__ float gelu_f(float x) {
    return 0.5f * x * (1.0f + erff(x * 0.7071067811865476f));
}

// Power-of-2 blockDim tree reduction. All threads must call.
__device__ __forceinline__ float block_sum(float v, float* scratch) {
    int tid = threadIdx.x;
    scratch[tid] = v;
    __syncthreads();
    for (int s = blockDim.x >> 1; s > 0; s >>= 1) {
        if (tid < s) scratch[tid] += scratch[tid + s];
        __syncthreads();
    }
    float r = scratch[0];
    __syncthreads();
    return r;
}

// ---------------------------------------------------------------------------
// K1: b1[b,t,m] = r5[m] + sum_n x*A55[m,n] + 0.1*nl + bl_bias[m], t in [0,T-1)
__global__ void k_b1(const float* __restrict__ vs, const float* __restrict__ r5,
                     const float* __restrict__ A55, const float* __restrict__ bl_bias,
                     const float* __restrict__ nlW1, const float* __restrict__ nlb1,
                     const float* __restrict__ nlW2, const float* __restrict__ nlb2,
                     float* __restrict__ b1w) {
    int idx = blockIdx.x * blockDim.x + threadIdx.x;
    if (idx >= B_ * (T_ - 1)) return;
    int b = idx / (T_ - 1), t = idx % (T_ - 1);
    float x[N_];
    for (int n = 0; n < N_; n++) x[n] = vs[(b * T_ + t) * N_ + n];
    float h[MLPH_];
    for (int j = 0; j < MLPH_; j++) {
        float a = nlb1[j];
        for (int n = 0; n < N_; n++) a += x[n] * nlW1[j * N_ + n];
        h[j] = gelu_f(a);
    }
    for (int m = 0; m < N_; m++) {
        float lin = r5[m];
        for (int n = 0; n < N_; n++) lin += x[n] * A55[m * N_ + n];
        float nl = nlb2[m];
        for (int j = 0; j < MLPH_; j++) nl += h[j] * nlW2[m * MLPH_ + j];
        b1w[idx * N_ + m] = lin + NL_SCALE_ * nl + bl_bias[m];
    }
}

// ---------------------------------------------------------------------------
// K2: residuals[b,t,n,si] for SCALES = {1,2,3,5}
__global__ void k_resid(const float* __restrict__ vs, const float* __restrict__ b1w,
                        float* __restrict__ resid) {
    int idx = blockIdx.x * blockDim.x + threadIdx.x;
    if (idx >= B_ * T_ * N_) return;
    int b = idx / (T_ * N_);
    int t = (idx / N_) % T_;
    int n = idx % N_;
    const int SC[4] = {1, 2, 3, 5};
    float lx0 = logf(fmaxf(vs[(b * T_ + t) * N_ + n], 1e-6f));
    for (int si = 0; si < 4; si++) {
        int k = SC[si];
        float r = 0.0f;
        if (t < T_ - k) {
            float lx1 = logf(fmaxf(vs[(b * T_ + t + k) * N_ + n], 1e-6f));
            float a = lx1 - lx0;
            float cmin = -2.5f * (float)k, cmax = 2.0f * (float)k;
            a = fminf(fmaxf(a, cmin), cmax);
            float bk = 0.0f;
            for (int i = 0; i < k; i++) bk += b1w[(b * (T_ - 1) + t + i) * N_ + n];
            r = a - bk;
        }
        resid[idx * 4 + si] = r;
    }
}

// ---------------------------------------------------------------------------
// K3: per-token MLP 16->128->128 + LN + PE, write transposed xt[(b*N+n)*T+t][d]
__global__ void k_mlp(const float* __restrict__ resid, const float* __restrict__ W1,
                      const float* __restrict__ b1, const float* __restrict__ W2,
                      const float* __restrict__ b2, const float* __restrict__ g,
                      const float* __restrict__ be, float* __restrict__ xt) {
    int tok = blockIdx.x;                 // over B*T*N
    int b = tok / (T_ * N_);
    int t = (tok / N_) % T_;
    int n = tok % N_;
    int d = threadIdx.x;                  // 128
    __shared__ float f[16];
    __shared__ float h1[D_];
    __shared__ float scratch[D_];
    if (d < 16) {
        int lag = d >> 2;
        int si = d & 3;
        f[d] = (t - lag >= 0) ? resid[((b * T_ + (t - lag)) * N_ + n) * 4 + si] : 0.0f;
    }
    __syncthreads();
    float a = b1[d];
    const float* w1r = W1 + d * 16;
    for (int c = 0; c < 16; c++) a += f[c] * w1r[c];
    h1[d] = gelu_f(a);
    __syncthreads();
    float a2 = b2[d];
    const float4* w2r = (const float4*)(W2 + d * D_);
    const float4* h14 = (const float4*)h1;
    for (int j = 0; j < D_ / 4; j++) {
        float4 w = w2r[j]; float4 x = h14[j];
        a2 += w.x * x.x + w.y * x.y + w.z * x.z + w.w * x.w;
    }
    float v = gelu_f(a2);
    float mean = block_sum(v, scratch) * (1.0f / D_);
    float dv = v - mean;
    float var = block_sum(dv * dv, scratch) * (1.0f / D_);
    float y = dv * rsqrtf(var + 1e-5f) * g[d] + be[d];
    int j = d >> 1;
    float freq = expf((float)(2 * j) * (-logf(10000.0f) / (float)D_));
    float ang = (float)t * freq;
    y += (d & 1) ? cosf(ang) : sinf(ang);
    xt[((b * N_ + n) * T_ + t) * D_ + d] = y;
}

// ---------------------------------------------------------------------------
// K4: encoder QKV projection. block = token (s*T+t), 384 threads.
__global__ void k_qkv_enc(const float* __restrict__ xt, const float* __restrict__ W,
                          const float* __restrict__ bias, float* __restrict__ Qb,
                          float* __restrict__ Kb, float* __restrict__ Vb) {
    int tok = blockIdx.x;                 // s*T + t
    int s = tok / T_, t = tok % T_;
    int tid = threadIdx.x;                // 0..383
    __shared__ float xv[D_];
    if (tid < D_) xv[tid] = xt[tok * D_ + tid];
    __syncthreads();
    float a = bias[tid];
    const float4* wr = (const float4*)(W + (size_t)tid * D_);
    const float4* xv4 = (const float4*)xv;
    for (int j = 0; j < D_ / 4; j++) {
        float4 w = wr[j]; float4 x = xv4[j];
        a += w.x * x.x + w.y * x.y + w.z * x.z + w.w * x.w;
    }
    int which = tid >> 7;                 // 0=Q 1=K 2=V
    int o = tid & 127;
    int h = o >> 5, dd = o & 31;
    float* dst = (which == 0) ? Qb : (which == 1) ? Kb : Vb;
    dst[((s * NH_ + h) * T_ + t) * HD_ + dd] = a;
}

// ---------------------------------------------------------------------------
// K5: cross QKV. Q from state_emb token, K/V from encoder output (remapped).
__global__ void k_qkv_cross(const float* __restrict__ semb, const float* __restrict__ xt,
                            const float* __restrict__ Wq, const float* __restrict__ bq,
                            const float* __restrict__ Wk, const float* __restrict__ bk,
                            const float* __restrict__ Wv, const float* __restrict__ bv,
                            float* __restrict__ Qb, float* __restrict__ Kb,
                            float* __restrict__ Vb) {
    int tok = blockIdx.x;                 // b*2048 + l
    int b = tok >> 11;
    int l = tok & 2047;
    int t = l >> 3, n = l & 7;
    int tid = threadIdx.x;                // 0..383
    __shared__ float sv[D_], rv[D_];
    if (tid < D_) {
        sv[tid] = semb[(size_t)tok * D_ + tid];
        rv[tid] = xt[((b * N_ + n) * T_ + t) * D_ + tid];
    }
    __syncthreads();
    int which = tid >> 7;
    int o = tid & 127;
    const float* W = (which == 0) ? Wq : (which == 1) ? Wk : Wv;
    const float* bb = (which == 0) ? bq : (which == 1) ? bk : bv;
    const float* src = (which == 0) ? sv : rv;
    float a = bb[o];
    const float4* wr = (const float4*)(W + (size_t)o * D_);
    const float4* s4 = (const float4*)src;
    for (int j = 0; j < D_ / 4; j++) {
        float4 w = wr[j]; float4 x = s4[j];
        a += w.x * x.x + w.y * x.y + w.z * x.z + w.w * x.w;
    }
    int h = o >> 5, dd = o & 31;
    float* dst = (which == 0) ? Qb : (which == 1) ? Kb : Vb;
    dst[((b * NH_ + h) * 2048 + l) * HD_ + dd] = a;
}

// ---------------------------------------------------------------------------
// K6: flash attention, thread-per-query, online softmax, K/V tiled in LDS.
// grid = NSH * (Lq/256) * NS. Block = 256 threads.
// NS==1: write normalized output to att[(s*Lq+q)*D + h*HD + d].
// NS>1 : write partial record {acc[32], m, l} (stride 36 floats) to part.
__global__ __launch_bounds__(256) void k_attn2(
    const float* __restrict__ Qb, const float* __restrict__ Kb,
    const float* __restrict__ Vb, float* __restrict__ att,
    float* __restrict__ part, int Lq, int Lk, int NSH, int NS) {
    int nqb = Lq >> 8;
    int bid = blockIdx.x;
    int split = bid % NS;
    int qblk = (bid / NS) % nqb;
    int sh = bid / (NS * nqb);
    int tid = threadIdx.x;
    int q = (qblk << 8) + tid;
    int klen = Lk / NS;
    int kbeg = split * klen;

    __shared__ float Ks[TK2][HD_];
    __shared__ float Vs[TK2][HD_];

    const float* Qp = Qb + ((size_t)sh * Lq + q) * HD_;
    const float* Kp = Kb + ((size_t)sh * Lk + kbeg) * HD_;
    const float* Vp = Vb + ((size_t)sh * Lk + kbeg) * HD_;

    const float scale = 0.17677669529663687f;  // 1/sqrt(32)
    float qv[HD_];
#pragma unroll
    for (int j = 0; j < 8; j++) {
        float4 t = ((const float4*)Qp)[j];
        qv[4 * j + 0] = t.x * scale; qv[4 * j + 1] = t.y * scale;
        qv[4 * j + 2] = t.z * scale; qv[4 * j + 3] = t.w * scale;
    }
    float m = -1e30f, l = 0.0f;
    float acc[HD_];
#pragma unroll
    for (int d = 0; d < HD_; d++) acc[d] = 0.0f;

    for (int k0 = 0; k0 < klen; k0 += TK2) {
        __syncthreads();
        // stage TK2*32 floats = 256 float4 each for K and V; 1 float4/thread
        ((float4*)&Ks[0][0])[tid] = ((const float4*)(Kp + (size_t)k0 * HD_))[tid];
        ((float4*)&Vs[0][0])[tid] = ((const float4*)(Vp + (size_t)k0 * HD_))[tid];
        __syncthreads();

        float sc[TK2];
#pragma unroll
        for (int kk = 0; kk < TK2; kk++) {
            const float4* kr = (const float4*)&Ks[kk][0];
            float a = 0.0f;
#pragma unroll
            for (int j = 0; j < 8; j++) {
                float4 kv = kr[j];
                a += qv[4 * j] * kv.x + qv[4 * j + 1] * kv.y +
                     qv[4 * j + 2] * kv.z + qv[4 * j + 3] * kv.w;
            }
            sc[kk] = a;
        }
        float tmax = sc[0];
#pragma unroll
        for (int kk = 1; kk < TK2; kk++) tmax = fmaxf(tmax, sc[kk]);
        float mn = fmaxf(m, tmax);
        float corr = __expf(m - mn);
        m = mn;
        l *= corr;
#pragma unroll
        for (int d = 0; d < HD_; d++) acc[d] *= corr;
#pragma unroll
        for (int kk = 0; kk < TK2; kk++) {
            float e = __expf(sc[kk] - mn);
            l += e;
            const float4* vr = (const float4*)&Vs[kk][0];
#pragma unroll
            for (int j = 0; j < 8; j++) {
                float4 vv = vr[j];
                acc[4 * j + 0] += e * vv.x; acc[4 * j + 1] += e * vv.y;
                acc[4 * j + 2] += e * vv.z; acc[4 * j + 3] += e * vv.w;
            }
        }
    }

    if (NS == 1) {
        int s = sh / NH_, h = sh % NH_;
        float inv = 1.0f / l;
        float* op = att + ((size_t)s * Lq + q) * D_ + h * HD_;
#pragma unroll
        for (int j = 0; j < 8; j++) {
            float4 o;
            o.x = acc[4 * j + 0] * inv; o.y = acc[4 * j + 1] * inv;
            o.z = acc[4 * j + 2] * inv; o.w = acc[4 * j + 3] * inv;
            ((float4*)op)[j] = o;
        }
    } else {
        float* rec = part + ((size_t)(split * NSH + sh) * Lq + q) * 36;
#pragma unroll
        for (int j = 0; j < 8; j++) {
            float4 o;
            o.x = acc[4 * j + 0]; o.y = acc[4 * j + 1];
            o.z = acc[4 * j + 2]; o.w = acc[4 * j + 3];
            ((float4*)rec)[j] = o;
        }
        rec[32] = m; rec[33] = l;
    }
}

// ---------------------------------------------------------------------------
// K6b: combine NS split-K partials -> normalized attention output.
__global__ void k_attn_comb(const float* __restrict__ part, float* __restrict__ att,
                            int Lq, int NSH, int NS) {
    int idx = blockIdx.x * blockDim.x + threadIdx.x;  // over NSH*Lq
    if (idx >= NSH * Lq) return;
    int sh = idx / Lq, q = idx % Lq;
    int s = sh / NH_, h = sh % NH_;
    float M = -1e30f;
    for (int sp = 0; sp < NS; sp++)
        M = fmaxf(M, part[((size_t)(sp * NSH + sh) * Lq + q) * 36 + 32]);
    float L = 0.0f;
    float acc[HD_];
#pragma unroll
    for (int d = 0; d < HD_; d++) acc[d] = 0.0f;
    for (int sp = 0; sp < NS; sp++) {
        const float* rec = part + ((size_t)(sp * NSH + sh) * Lq + q) * 36;
        float e = __expf(rec[32] - M);
        L += rec[33] * e;
#pragma unroll
        for (int j = 0; j < 8; j++) {
            float4 a = ((const float4*)rec)[j];
            acc[4 * j + 0] += a.x * e; acc[4 * j + 1] += a.y * e;
            acc[4 * j + 2] += a.z * e; acc[4 * j + 3] += a.w * e;
        }
    }
    float inv = 1.0f / L;
    float* op = att + ((size_t)s * Lq + q) * D_ + h * HD_;
#pragma unroll
    for (int j = 0; j < 8; j++) {
        float4 o;
        o.x = acc[4 * j + 0] * inv; o.y = acc[4 * j + 1] * inv;
        o.z = acc[4 * j + 2] * inv; o.w = acc[4 * j + 3] * inv;
        ((float4*)op)[j] = o;
    }
}

// ---------------------------------------------------------------------------
// K7: out-projection + residual + LN. block = token, 128 threads.
__global__ void k_outproj_ln(const float* __restrict__ att, const float* __restrict__ Wo,
                             const float* __restrict__ bo, const float* __restrict__ xin,
                             const float* __restrict__ g, const float* __restrict__ be,
                             float* __restrict__ xout) {
    int tok = blockIdx.x;
    int d = threadIdx.x;
    __shared__ float av[D_];
    __shared__ float scratch[D_];
    av[d] = att[(size_t)tok * D_ + d];
    __syncthreads();
    float a = bo[d];
    const float4* wr = (const float4*)(Wo + (size_t)d * D_);
    const float4* av4 = (const float4*)av;
    for (int j = 0; j < D_ / 4; j++) {
        float4 w = wr[j]; float4 x = av4[j];
        a += w.x * x.x + w.y * x.y + w.z * x.z + w.w * x.w;
    }
    float v = xin[(size_t)tok * D_ + d] + a;
    float mean = block_sum(v, scratch) * (1.0f / D_);
    float dv = v - mean;
    float var = block_sum(dv * dv, scratch) * (1.0f / D_);
    xout[(size_t)tok * D_ + d] = dv * rsqrtf(var + 1e-5f) * g[d] + be[d];
}

// ---------------------------------------------------------------------------
// K8: encoder FF 128->256->128 + residual + LN. block = token, 256 threads.
__global__ void k_ff_enc(const float* __restrict__ xin, const float* __restrict__ W1,
                         const float* __restrict__ b1, const float* __restrict__ W2,
                         const float* __restrict__ b2, const float* __restrict__ g,
                         const float* __restrict__ be, float* __restrict__ xout) {
    int tok = blockIdx.x;
    int tid = threadIdx.x;                // 0..255
    __shared__ float xv[D_];
    __shared__ float h[256];
    __shared__ float scratch[256];
    if (tid < D_) xv[tid] = xin[(size_t)tok * D_ + tid];
    __syncthreads();
    float a = b1[tid];
    const float4* wr = (const float4*)(W1 + (size_t)tid * D_);
    const float4* xv4 = (const float4*)xv;
    for (int j = 0; j < D_ / 4; j++) {
        float4 w = wr[j]; float4 x = xv4[j];
        a += w.x * x.x + w.y * x.y + w.z * x.z + w.w * x.w;
    }
    h[tid] = gelu_f(a);
    __syncthreads();
    float v = 0.0f;
    if (tid < D_) {
        float a2 = b2[tid];
        const float4* w2 = (const float4*)(W2 + (size_t)tid * 256);
        const float4* h4 = (const float4*)h;
        for (int j = 0; j < 256 / 4; j++) {
            float4 w = w2[j]; float4 x = h4[j];
            a2 += w.x * x.x + w.y * x.y + w.z * x.z + w.w * x.w;
        }
        v = xv[tid] + a2;
    }
    float mean = block_sum(v, scratch) * (1.0f / D_);
    float dv = (tid < D_) ? (v - mean) : 0.0f;
    float var = block_sum(dv * dv, scratch) * (1.0f / D_);
    if (tid < D_)
        xout[(size_t)tok * D_ + tid] = dv * rsqrtf(var + 1e-5f) * g[tid] + be[tid];
}

// ---------------------------------------------------------------------------
// K9: cross fused FF: concat([s1, r]) 256 -> 512 -> 128, +s1, LN. 512 threads.
__global__ void k_ff_cross(const float* __restrict__ S1, const float* __restrict__ xt,
                           const float* __restrict__ W1, const float* __restrict__ b1,
                           const float* __restrict__ W2, const float* __restrict__ b2,
                           const float* __restrict__ g, const float* __restrict__ be,
                           float* __restrict__ out) {
    int tok = blockIdx.x;                 // b*2048 + l
    int b = tok >> 11;
    int l = tok & 2047;
    int t = l >> 3, n = l & 7;
    int tid = threadIdx.x;                // 0..511
    __shared__ float cat[256];
    __shared__ float h[512];
    __shared__ float scratch[512];
    if (tid < D_) cat[tid] = S1[(size_t)tok * D_ + tid];
    else if (tid < 256) cat[tid] = xt[((b * N_ + n) * T_ + t) * D_ + (tid - D_)];
    __syncthreads();
    float a = b1[tid];
    const float4* wr = (const float4*)(W1 + (size_t)tid * 256);
    const float4* c4 = (const float4*)cat;
    for (int j = 0; j < 256 / 4; j++) {
        float4 w = wr[j]; float4 x = c4[j];
        a += w.x * x.x + w.y * x.y + w.z * x.z + w.w * x.w;
    }
    h[tid] = gelu_f(a);
    __syncthreads();
    float v = 0.0f;
    if (tid < D_) {
        float a2 = b2[tid];
        const float4* w2 = (const float4*)(W2 + (size_t)tid * 512);
        const float4* h4 = (const float4*)h;
        for (int j = 0; j < 512 / 4; j++) {
            float4 w = w2[j]; float4 x = h4[j];
            a2 += w.x * x.x + w.y * x.y + w.z * x.z + w.w * x.w;
        }
        v = cat[tid] + a2;                // s1 + fused
    }
    float mean = block_sum(v, scratch) * (1.0f / D_);
    float dv = (tid < D_) ? (v - mean) : 0.0f;
    float var = block_sum(dv * dv, scratch) * (1.0f / D_);
    if (tid < D_)
        out[(size_t)tok * D_ + tid] = dv * rsqrtf(var + 1e-5f) * g[tid] + be[tid];
}

// ---------------------------------------------------------------------------
extern "C" void kernel_launch(void* const* d_in, const int* in_sizes, int n_in,
                              void* d_out, int out_size, void* d_ws, size_t ws_size,
                              hipStream_t stream) {
    const float* vs       = (const float*)d_in[0];
    const float* semb     = (const float*)d_in[1];
    const float* r5       = (const float*)d_in[2];
    const float* A55      = (const float*)d_in[3];
    const float* bl_bias  = (const float*)d_in[4];
    const float* nl_W1    = (const float*)d_in[5];
    const float* nl_b1    = (const float*)d_in[6];
    const float* nl_W2    = (const float*)d_in[7];
    const float* nl_b2    = (const float*)d_in[8];
    const float* mlp_W1   = (const float*)d_in[9];
    const float* mlp_b1   = (const float*)d_in[10];
    const float* mlp_W2   = (const float*)d_in[11];
    const float* mlp_b2   = (const float*)d_in[12];
    const float* mlp_ln_g = (const float*)d_in[13];
    const float* mlp_ln_b = (const float*)d_in[14];
    const float* enc_qkv_W = (const float*)d_in[15];
    const float* enc_qkv_b = (const float*)d_in[16];
    const float* enc_out_W = (const float*)d_in[17];
    const float* enc_out_b = (const float*)d_in[18];
    const float* enc_ln1_g = (const float*)d_in[19];
    const float* enc_ln1_b = (const float*)d_in[20];
    const float* enc_ff_W1 = (const float*)d_in[21];
    const float* enc_ff_b1 = (const float*)d_in[22];
    const float* enc_ff_W2 = (const float*)d_in[23];
    const float* enc_ff_b2 = (const float*)d_in[24];
    const float* enc_ln2_g = (const float*)d_in[25];
    const float* enc_ln2_b = (const float*)d_in[26];
    const float* ca_Wq = (const float*)d_in[27];
    const float* ca_bq = (const float*)d_in[28];
    const float* ca_Wk = (const float*)d_in[29];
    const float* ca_bk = (const float*)d_in[30];
    const float* ca_Wv = (const float*)d_in[31];
    const float* ca_bv = (const float*)d_in[32];
    const float* ca_Wo = (const float*)d_in[33];
    const float* ca_bo = (const float*)d_in[34];
    const float* ca_ln1_g = (const float*)d_in[35];
    const float* ca_ln1_b = (const float*)d_in[36];
    const float* ca_ff_W1 = (const float*)d_in[37];
    const float* ca_ff_b1 = (const float*)d_in[38];
    const float* ca_ff_W2 = (const float*)d_in[39];
    const float* ca_ff_b2 = (const float*)d_in[40];
    const float* ca_ln2_g = (const float*)d_in[41];
    const float* ca_ln2_b = (const float*)d_in[42];
    float* out = (float*)d_out;

    // Workspace layout (floats)
    float* ws = (float*)d_ws;
    float* b1w   = ws;                        // 8192
    float* resid = ws + 8192;                 // 32768
    float* X0    = ws + 8192 + 32768;         // 1048576
    float* X1    = X0 + 1048576;
    float* Qbuf  = X1 + 1048576;
    float* Kbuf  = Qbuf + 1048576;
    float* Vbuf  = Kbuf + 1048576;
    float* ATT   = Vbuf + 1048576;
    float* part  = ATT + 1048576;             // split-K partials (optional)
    const size_t base_floats = 6332416;       // everything up to and incl. ATT

    // Pick cross-attention split factor by available workspace.
    // Partial record = 36 floats per (split, sh, q); cross: NSH=16, Lq=2048.
    int NS_cross = 1;
    {
        size_t avail = ws_size / 4;
        if (avail >= base_floats + (size_t)4 * 16 * 2048 * 36) NS_cross = 4;
        else if (avail >= base_floats + (size_t)2 * 16 * 2048 * 36) NS_cross = 2;
    }

    const int NTOK = B_ * T_ * N_;            // 8192

    k_b1<<<dim3((B_ * (T_ - 1) + 63) / 64), dim3(64), 0, stream>>>(
        vs, r5, A55, bl_bias, nl_W1, nl_b1, nl_W2, nl_b2, b1w);

    k_resid<<<dim3(NTOK / 64), dim3(64), 0, stream>>>(vs, b1w, resid);

    k_mlp<<<dim3(NTOK), dim3(128), 0, stream>>>(
        resid, mlp_W1, mlp_b1, mlp_W2, mlp_b2, mlp_ln_g, mlp_ln_b, X0);

    // Encoder layers: NSH = 32 seqs * 4 heads = 128, Lq = Lk = 256, NS = 1.
    for (int i = 0; i < LENC_; i++) {
        const float* qkvW = enc_qkv_W + (size_t)i * 384 * 128;
        const float* qkvB = enc_qkv_b + (size_t)i * 384;
        k_qkv_enc<<<dim3(NTOK), dim3(384), 0, stream>>>(X0, qkvW, qkvB, Qbuf, Kbuf, Vbuf);
        k_attn2<<<dim3(128 * (T_ / 256) * 1), dim3(256), 0, stream>>>(
            Qbuf, Kbuf, Vbuf, ATT, part, T_, T_, 128, 1);
        k_outproj_ln<<<dim3(NTOK), dim3(128), 0, stream>>>(
            ATT, enc_out_W + (size_t)i * 128 * 128, enc_out_b + (size_t)i * 128, X0,
            enc_ln1_g + (size_t)i * 128, enc_ln1_b + (size_t)i * 128, X1);
        k_ff_enc<<<dim3(NTOK), dim3(256), 0, stream>>>(
            X1, enc_ff_W1 + (size_t)i * 256 * 128, enc_ff_b1 + (size_t)i * 256,
            enc_ff_W2 + (size_t)i * 128 * 256, enc_ff_b2 + (size_t)i * 128,
            enc_ln2_g + (size_t)i * 128, enc_ln2_b + (size_t)i * 128, X0);
    }

    // Cross-attention: NSH = 4 batches * 4 heads = 16, Lq = Lk = 2048.
    k_qkv_cross<<<dim3(NTOK), dim3(384), 0, stream>>>(
        semb, X0, ca_Wq, ca_bq, ca_Wk, ca_bk, ca_Wv, ca_bv, Qbuf, Kbuf, Vbuf);
    k_attn2<<<dim3(16 * (2048 / 256) * NS_cross), dim3(256), 0, stream>>>(
        Qbuf, Kbuf, Vbuf, ATT, part, 2048, 2048, 16, NS_cross);
    if (NS_cross > 1) {
        k_attn_comb<<<dim3((16 * 2048 + 255) / 256), dim3(256), 0, stream>>>(
            part, ATT, 2048, 16, NS_cross);
    }
    k_outproj_ln<<<dim3(NTOK), dim3(128), 0, stream>>>(
        ATT, ca_Wo, ca_bo, semb, ca_ln1_g, ca_ln1_b, X1);  // X1 = s1
    k_ff_cross<<<dim3(NTOK), dim3(512), 0, stream>>>(
        X1, X0, ca_ff_W1, ca_ff_b1, ca_ff_W2, ca_ff_b2, ca_ln2_g, ca_ln2_b, out);
}

// Round 3
// 779.905 us; speedup vs baseline: 6.5927x; 3.2241x over previous
//
#include <hip/hip_runtime.h>
#include <math.h>

// Problem constants
#define B_ 4
#define T_ 256
#define N_ 8
#define D_ 128
#define NH_ 4
#define HD_ 32
#define LENC_ 2
#define MLPH_ 32
#define NL_SCALE_ 0.1f

typedef __bf16 bf16;
typedef __attribute__((ext_vector_type(8))) __bf16 bf16x8;
typedef __attribute__((ext_vector_type(4))) float f32x4;

__device__ __forceinline__ float gelu_f(float x) {
    return 0.5f * x * (1.0f + erff(x * 0.7071067811865476f));
}

// Power-of-2 blockDim tree reduction. All threads must call.
__device__ __forceinline__ float block_sum(float v, float* scratch) {
    int tid = threadIdx.x;
    scratch[tid] = v;
    __syncthreads();
    for (int s = blockDim.x >> 1; s > 0; s >>= 1) {
        if (tid < s) scratch[tid] += scratch[tid + s];
        __syncthreads();
    }
    float r = scratch[0];
    __syncthreads();
    return r;
}

// ---------------------------------------------------------------------------
// Weight pack: fp32 -> bf16, all projection weights into one buffer.
// Element offsets (hardcoded): see host side for the map.
__global__ void k_pack(const float* __restrict__ eqkvW, const float* __restrict__ eoutW,
                       const float* __restrict__ eff1, const float* __restrict__ eff2,
                       const float* __restrict__ wq, const float* __restrict__ wk,
                       const float* __restrict__ wv, const float* __restrict__ wo,
                       const float* __restrict__ cff1, const float* __restrict__ cff2,
                       const float* __restrict__ mlpW2, bf16* __restrict__ dst) {
    int i = blockIdx.x * 256 + threadIdx.x;
    if (i >= 540672) return;
    const float* src; int off;
    if      (i < 98304)  { src = eqkvW; off = 0; }
    else if (i < 131072) { src = eoutW; off = 98304; }
    else if (i < 196608) { src = eff1;  off = 131072; }
    else if (i < 262144) { src = eff2;  off = 196608; }
    else if (i < 278528) { src = wq;    off = 262144; }
    else if (i < 294912) { src = wk;    off = 278528; }
    else if (i < 311296) { src = wv;    off = 294912; }
    else if (i < 327680) { src = wo;    off = 311296; }
    else if (i < 458752) { src = cff1;  off = 327680; }
    else if (i < 524288) { src = cff2;  off = 458752; }
    else                 { src = mlpW2; off = 524288; }
    dst[i] = (bf16)src[i - off];
}

// bias pack for the cross KV gemm: [ca_bk ; ca_bv]
__global__ void k_bpack(const float* __restrict__ bk, const float* __restrict__ bv,
                        float* __restrict__ dst) {
    int t = threadIdx.x;
    dst[t] = (t < 128) ? bk[t] : bv[t - 128];
}

// fp32 -> bf16 flat convert (state_emb)
__global__ void k_tobf(const float* __restrict__ src, bf16* __restrict__ dst, int n) {
    int i = blockIdx.x * 256 + threadIdx.x;
    if (i < n) dst[i] = (bf16)src[i];
}

// ---------------------------------------------------------------------------
// K1: b1[b,t,m], t in [0,T-1)
__global__ void k_b1(const float* __restrict__ vs, const float* __restrict__ r5,
                     const float* __restrict__ A55, const float* __restrict__ bl_bias,
                     const float* __restrict__ nlW1, const float* __restrict__ nlb1,
                     const float* __restrict__ nlW2, const float* __restrict__ nlb2,
                     float* __restrict__ b1w) {
    int idx = blockIdx.x * blockDim.x + threadIdx.x;
    if (idx >= B_ * (T_ - 1)) return;
    int b = idx / (T_ - 1), t = idx % (T_ - 1);
    float x[N_];
    for (int n = 0; n < N_; n++) x[n] = vs[(b * T_ + t) * N_ + n];
    float h[MLPH_];
    for (int j = 0; j < MLPH_; j++) {
        float a = nlb1[j];
        for (int n = 0; n < N_; n++) a += x[n] * nlW1[j * N_ + n];
        h[j] = gelu_f(a);
    }
    for (int m = 0; m < N_; m++) {
        float lin = r5[m];
        for (int n = 0; n < N_; n++) lin += x[n] * A55[m * N_ + n];
        float nl = nlb2[m];
        for (int j = 0; j < MLPH_; j++) nl += h[j] * nlW2[m * MLPH_ + j];
        b1w[idx * N_ + m] = lin + NL_SCALE_ * nl + bl_bias[m];
    }
}

// ---------------------------------------------------------------------------
// K2: residuals[b,t,n,si] for SCALES = {1,2,3,5}
__global__ void k_resid(const float* __restrict__ vs, const float* __restrict__ b1w,
                        float* __restrict__ resid) {
    int idx = blockIdx.x * blockDim.x + threadIdx.x;
    if (idx >= B_ * T_ * N_) return;
    int b = idx / (T_ * N_);
    int t = (idx / N_) % T_;
    int n = idx % N_;
    const int SC[4] = {1, 2, 3, 5};
    float lx0 = logf(fmaxf(vs[(b * T_ + t) * N_ + n], 1e-6f));
    for (int si = 0; si < 4; si++) {
        int k = SC[si];
        float r = 0.0f;
        if (t < T_ - k) {
            float lx1 = logf(fmaxf(vs[(b * T_ + t + k) * N_ + n], 1e-6f));
            float a = lx1 - lx0;
            float cmin = -2.5f * (float)k, cmax = 2.0f * (float)k;
            a = fminf(fmaxf(a, cmin), cmax);
            float bk = 0.0f;
            for (int i = 0; i < k; i++) bk += b1w[(b * (T_ - 1) + t + i) * N_ + n];
            r = a - bk;
        }
        resid[idx * 4 + si] = r;
    }
}

// ---------------------------------------------------------------------------
// K3a: per-token MLP layer1 (16 -> 128, gelu), output bf16 in (b,t,n) order.
__global__ void k_mlp1(const float* __restrict__ resid, const float* __restrict__ W1,
                       const float* __restrict__ b1, bf16* __restrict__ H1h) {
    int tok = blockIdx.x;                  // b*2048 + t*8 + n
    int d = threadIdx.x;                   // 128
    int b = tok >> 11, t = (tok >> 3) & 255, n = tok & 7;
    __shared__ float f[16];
    if (d < 16) {
        int g = d >> 2, si = d & 3;        // group g: lag = g (LAGS=1,2,3)
        f[d] = (t - g >= 0) ? resid[((b * T_ + (t - g)) * N_ + n) * 4 + si] : 0.0f;
    }
    __syncthreads();
    float a = b1[d];
    const float* w = W1 + d * 16;
#pragma unroll
    for (int c = 0; c < 16; c++) a += f[c] * w[c];
    H1h[(size_t)tok * 128 + d] = (bf16)gelu_f(a);
}

// K3b: gelu(OF) -> LN -> +PE -> write X0 fp32 + bf16, transposed to xt order.
__global__ void k_mlp2(const float* __restrict__ OF, const float* __restrict__ g,
                       const float* __restrict__ be, float* __restrict__ X0,
                       bf16* __restrict__ X0h) {
    int tok = blockIdx.x;
    int d = threadIdx.x;
    int b = tok >> 11, t = (tok >> 3) & 255, n = tok & 7;
    __shared__ float scratch[128];
    float v = gelu_f(OF[(size_t)tok * 128 + d]);
    float mean = block_sum(v, scratch) * (1.0f / 128.0f);
    float dv = v - mean;
    float var = block_sum(dv * dv, scratch) * (1.0f / 128.0f);
    float y = dv * rsqrtf(var + 1e-5f) * g[d] + be[d];
    int j = d >> 1;
    float freq = expf((float)(2 * j) * (-9.210340371976184f / 128.0f));
    float ang = (float)t * freq;
    y += (d & 1) ? cosf(ang) : sinf(ang);
    size_t r = ((size_t)(b * 8 + n) * 256 + t) * 128 + d;
    X0[r] = y;
    X0h[r] = (bf16)y;
}

// ---------------------------------------------------------------------------
// MFMA GEMM: C[M x N] = act(A @ W^T + bias). A bf16 [MxK] rowmajor,
// W bf16 [NxK] rowmajor. One 16x16 C tile per wave; 4 waves/block.
// A-frag: m=lane&15, k=(lane>>4)*8+j ; B-frag (from W rows): n=lane&15, same k.
// C: col=lane&15, row=(lane>>4)*4+reg  [m89-verified].
__global__ __launch_bounds__(256) void k_gemm(
    const bf16* __restrict__ A, const bf16* __restrict__ W,
    const float* __restrict__ bias, float* __restrict__ Cf,
    bf16* __restrict__ Ch, int M, int N, int K, int act) {
    int lane = threadIdx.x & 63;
    int wv = threadIdx.x >> 6;
    int wtile = blockIdx.x * 4 + wv;
    int nN = N >> 4;
    int tn = wtile % nN, tm = wtile / nN;
    if (tm >= (M >> 4)) return;
    int mrow = tm * 16 + (lane & 15);
    int nrow = tn * 16 + (lane & 15);
    int g = lane >> 4;
    const bf16x8* Ap = (const bf16x8*)(A + (size_t)mrow * K) + g;
    const bf16x8* Wp = (const bf16x8*)(W + (size_t)nrow * K) + g;
    f32x4 acc = {0.0f, 0.0f, 0.0f, 0.0f};
    int nk = K >> 5;
    for (int k = 0; k < nk; k++) {
        bf16x8 av = Ap[k * 4];
        bf16x8 bv8 = Wp[k * 4];
        acc = __builtin_amdgcn_mfma_f32_16x16x32_bf16(av, bv8, acc, 0, 0, 0);
    }
    int col = tn * 16 + (lane & 15);
    int row0 = tm * 16 + g * 4;
    float bvv = bias[col];
#pragma unroll
    for (int i = 0; i < 4; i++) {
        float v = acc[i] + bvv;
        if (act) v = gelu_f(v);
        if (Cf) Cf[(size_t)(row0 + i) * N + col] = v;
        if (Ch) Ch[(size_t)(row0 + i) * N + col] = (bf16)v;
    }
}

// ---------------------------------------------------------------------------
// Flash attention, thread-per-query, online softmax, K/V tiles in LDS.
// mode 0 (encoder): sh in [0,128): s=sh>>2, h=sh&3. Q/K/V inside QKV[M x 384],
//   row = s*256 + idx; Q col h*32, K col 128+h*32, V col 256+h*32.
// mode 1 (cross): sh in [0,16): b=sh>>2, h=sh&3. Q from Qc[M x 128] row
//   b*2048+q; K/V from KV[M x 256] row (b*8+(l&7))*256+(l>>3), K col h*32,
//   V col 128+h*32.
// Output: bf16 ATTh[row*128 + h*32 + d] (NS==1) or fp32 partials (NS>1).
__global__ __launch_bounds__(256) void k_fattn(
    const float* __restrict__ Qsrc, const float* __restrict__ KV,
    bf16* __restrict__ ATTh, float* __restrict__ part,
    int Lk, int nqb, int NS, int mode) {
    int bid = blockIdx.x;
    int split = bid % NS;
    int qblk = (bid / NS) % nqb;
    int sh = bid / (NS * nqb);
    int tid = threadIdx.x;
    int q = qblk * 256 + tid;
    int klen = Lk / NS, kbeg = split * klen;
    int sb = sh >> 2, h = sh & 3;

    __shared__ float Ks[32][32];
    __shared__ float Vs[32][32];

    const float* Qp;
    if (mode == 0) Qp = Qsrc + ((size_t)(sb * 256 + q)) * 384 + h * 32;
    else           Qp = Qsrc + ((size_t)(sb * 2048 + q)) * 128 + h * 32;

    const float scale = 0.17677669529663687f;  // 1/sqrt(32)
    float qv[HD_];
#pragma unroll
    for (int j = 0; j < 8; j++) {
        float4 t4 = ((const float4*)Qp)[j];
        qv[4 * j + 0] = t4.x * scale; qv[4 * j + 1] = t4.y * scale;
        qv[4 * j + 2] = t4.z * scale; qv[4 * j + 3] = t4.w * scale;
    }
    float m = -1e30f, l = 0.0f;
    float acc[HD_];
#pragma unroll
    for (int d = 0; d < HD_; d++) acc[d] = 0.0f;

    int key = tid >> 3, f4 = tid & 7;
    for (int k0 = 0; k0 < klen; k0 += 32) {
        __syncthreads();
        int kidx = kbeg + k0 + key;
        const float* Krow;
        if (mode == 0) {
            Krow = KV + ((size_t)(sb * 256 + kidx)) * 384 + 128 + h * 32;
            ((float4*)&Ks[0][0])[tid] = ((const float4*)Krow)[f4];
            ((float4*)&Vs[0][0])[tid] = ((const float4*)(Krow + 128))[f4];
        } else {
            int r = (sb * 8 + (kidx & 7)) * 256 + (kidx >> 3);
            Krow = KV + ((size_t)r) * 256 + h * 32;
            ((float4*)&Ks[0][0])[tid] = ((const float4*)Krow)[f4];
            ((float4*)&Vs[0][0])[tid] = ((const float4*)(Krow + 128))[f4];
        }
        __syncthreads();

        float sc[32];
#pragma unroll
        for (int kk = 0; kk < 32; kk++) {
            const float4* kr = (const float4*)&Ks[kk][0];
            float a = 0.0f;
#pragma unroll
            for (int j = 0; j < 8; j++) {
                float4 kvv = kr[j];
                a += qv[4 * j] * kvv.x + qv[4 * j + 1] * kvv.y +
                     qv[4 * j + 2] * kvv.z + qv[4 * j + 3] * kvv.w;
            }
            sc[kk] = a;
        }
        float tmax = sc[0];
#pragma unroll
        for (int kk = 1; kk < 32; kk++) tmax = fmaxf(tmax, sc[kk]);
        float mn = fmaxf(m, tmax);
        float corr = __expf(m - mn);
        m = mn;
        l *= corr;
#pragma unroll
        for (int d = 0; d < HD_; d++) acc[d] *= corr;
#pragma unroll
        for (int kk = 0; kk < 32; kk++) {
            float e = __expf(sc[kk] - mn);
            l += e;
            const float4* vr = (const float4*)&Vs[kk][0];
#pragma unroll
            for (int j = 0; j < 8; j++) {
                float4 vvv = vr[j];
                acc[4 * j + 0] += e * vvv.x; acc[4 * j + 1] += e * vvv.y;
                acc[4 * j + 2] += e * vvv.z; acc[4 * j + 3] += e * vvv.w;
            }
        }
    }

    if (NS == 1) {
        int row = (mode == 0) ? (sb * 256 + q) : (sb * 2048 + q);
        float inv = 1.0f / l;
        bf16x8* op = (bf16x8*)(ATTh + (size_t)row * 128 + h * 32);
#pragma unroll
        for (int j = 0; j < 4; j++) {
            bf16x8 o;
#pragma unroll
            for (int e = 0; e < 8; e++) o[e] = (bf16)(acc[8 * j + e] * inv);
            op[j] = o;
        }
    } else {
        float* rec = part + ((size_t)(split * 16 + sh) * 2048 + q) * 36;
#pragma unroll
        for (int j = 0; j < 8; j++) {
            float4 o;
            o.x = acc[4 * j + 0]; o.y = acc[4 * j + 1];
            o.z = acc[4 * j + 2]; o.w = acc[4 * j + 3];
            ((float4*)rec)[j] = o;
        }
        rec[32] = m; rec[33] = l;
    }
}

// Combine NS split-K partials -> bf16 attention output (cross only).
__global__ void k_comb(const float* __restrict__ part, bf16* __restrict__ ATTh,
                       int NS) {
    int idx = blockIdx.x * blockDim.x + threadIdx.x;  // over 16*2048
    if (idx >= 16 * 2048) return;
    int sh = idx >> 11, q = idx & 2047;
    int sb = sh >> 2, h = sh & 3;
    float M = -1e30f;
    for (int sp = 0; sp < NS; sp++)
        M = fmaxf(M, part[((size_t)(sp * 16 + sh) * 2048 + q) * 36 + 32]);
    float L = 0.0f;
    float acc[HD_];
#pragma unroll
    for (int d = 0; d < HD_; d++) acc[d] = 0.0f;
    for (int sp = 0; sp < NS; sp++) {
        const float* rec = part + ((size_t)(sp * 16 + sh) * 2048 + q) * 36;
        float e = __expf(rec[32] - M);
        L += rec[33] * e;
#pragma unroll
        for (int j = 0; j < 8; j++) {
            float4 a = ((const float4*)rec)[j];
            acc[4 * j + 0] += a.x * e; acc[4 * j + 1] += a.y * e;
            acc[4 * j + 2] += a.z * e; acc[4 * j + 3] += a.w * e;
        }
    }
    float inv = 1.0f / L;
    bf16x8* op = (bf16x8*)(ATTh + ((size_t)sb * 2048 + q) * 128 + h * 32);
#pragma unroll
    for (int j = 0; j < 4; j++) {
        bf16x8 o;
#pragma unroll
        for (int e = 0; e < 8; e++) o[e] = (bf16)(acc[8 * j + e] * inv);
        op[j] = o;
    }
}

// ---------------------------------------------------------------------------
// Residual + LN: y = LN(xin + delta)*g + be. Writes fp32 (if xf) and bf16
// (if xh, with row stride hstride — used to write into the CAT buffer).
__global__ void k_ln_res(const float* __restrict__ xin, const float* __restrict__ delta,
                         const float* __restrict__ g, const float* __restrict__ be,
                         float* __restrict__ xf, bf16* __restrict__ xh, int hstride) {
    int tok = blockIdx.x;
    int d = threadIdx.x;
    __shared__ float scratch[128];
    float v = xin[(size_t)tok * 128 + d] + delta[(size_t)tok * 128 + d];
    float mean = block_sum(v, scratch) * (1.0f / 128.0f);
    float dv = v - mean;
    float var = block_sum(dv * dv, scratch) * (1.0f / 128.0f);
    float y = dv * rsqrtf(var + 1e-5f) * g[d] + be[d];
    if (xf) xf[(size_t)tok * 128 + d] = y;
    if (xh) xh[(size_t)tok * hstride + d] = (bf16)y;
}

// Fill CAT[:,128:256] from encoder output X0h (xt order -> (b,t,n) order).
__global__ void k_cat(const bf16* __restrict__ X0h, bf16* __restrict__ CATh) {
    int i = blockIdx.x * 256 + threadIdx.x;   // over 1048576
    if (i >= 1048576) return;
    int tok = i >> 7, d = i & 127;
    int b = tok >> 11, t = (tok >> 3) & 255, n = tok & 7;
    CATh[(size_t)tok * 256 + 128 + d] = X0h[((size_t)(b * 8 + n) * 256 + t) * 128 + d];
}

// ---------------------------------------------------------------------------
extern "C" void kernel_launch(void* const* d_in, const int* in_sizes, int n_in,
                              void* d_out, int out_size, void* d_ws, size_t ws_size,
                              hipStream_t stream) {
    const float* vs       = (const float*)d_in[0];
    const float* semb     = (const float*)d_in[1];
    const float* r5       = (const float*)d_in[2];
    const float* A55      = (const float*)d_in[3];
    const float* bl_bias  = (const float*)d_in[4];
    const float* nl_W1    = (const float*)d_in[5];
    const float* nl_b1    = (const float*)d_in[6];
    const float* nl_W2    = (const float*)d_in[7];
    const float* nl_b2    = (const float*)d_in[8];
    const float* mlp_W1   = (const float*)d_in[9];
    const float* mlp_b1   = (const float*)d_in[10];
    const float* mlp_W2   = (const float*)d_in[11];
    const float* mlp_b2   = (const float*)d_in[12];
    const float* mlp_ln_g = (const float*)d_in[13];
    const float* mlp_ln_b = (const float*)d_in[14];
    const float* enc_qkv_W = (const float*)d_in[15];
    const float* enc_qkv_b = (const float*)d_in[16];
    const float* enc_out_W = (const float*)d_in[17];
    const float* enc_out_b = (const float*)d_in[18];
    const float* enc_ln1_g = (const float*)d_in[19];
    const float* enc_ln1_b = (const float*)d_in[20];
    const float* enc_ff_W1 = (const float*)d_in[21];
    const float* enc_ff_b1 = (const float*)d_in[22];
    const float* enc_ff_W2 = (const float*)d_in[23];
    const float* enc_ff_b2 = (const float*)d_in[24];
    const float* enc_ln2_g = (const float*)d_in[25];
    const float* enc_ln2_b = (const float*)d_in[26];
    const float* ca_Wq = (const float*)d_in[27];
    const float* ca_bq = (const float*)d_in[28];
    const float* ca_Wk = (const float*)d_in[29];
    const float* ca_bk = (const float*)d_in[30];
    const float* ca_Wv = (const float*)d_in[31];
    const float* ca_bv = (const float*)d_in[32];
    const float* ca_Wo = (const float*)d_in[33];
    const float* ca_bo = (const float*)d_in[34];
    const float* ca_ln1_g = (const float*)d_in[35];
    const float* ca_ln1_b = (const float*)d_in[36];
    const float* ca_ff_W1 = (const float*)d_in[37];
    const float* ca_ff_b1 = (const float*)d_in[38];
    const float* ca_ff_W2 = (const float*)d_in[39];
    const float* ca_ff_b2 = (const float*)d_in[40];
    const float* ca_ln2_g = (const float*)d_in[41];
    const float* ca_ln2_b = (const float*)d_in[42];
    float* out = (float*)d_out;

    // Workspace layout (byte offsets, 256-aligned)
    char* base = (char*)d_ws;
    float* b1w   = (float*)(base + 0);          //  32 KB
    float* resid = (float*)(base + 32768);      // 128 KB
    float* X0    = (float*)(base + 163840);     //   4 MB
    float* X1    = (float*)(base + 4358144);    //   4 MB
    float* QKV   = (float*)(base + 8552448);    //  12 MB (enc QKV; cross Qc+KV; then CATh+Hh)
    float* OF    = (float*)(base + 21135360);   //   4 MB
    bf16*  Wpk   = (bf16*) (base + 25329664);   // 1.03 MB
    float* bpk   = (float*)(base + 26411008);   //   1 KB
    bf16*  X0h   = (bf16*) (base + 26412032);   //   2 MB
    bf16*  X1h   = (bf16*) (base + 28509184);   //   2 MB
    bf16*  sembh = (bf16*) (base + 30606336);   //   2 MB
    bf16*  ATTh  = (bf16*) (base + 32703488);   //   2 MB
    float* part  = (float*)(base + 34800640);   // NS * 4.5 MB
    float* Qc    = QKV;                         // cross: Q [8192x128] fp32
    float* KVb   = QKV + 1048576;               // cross: KV [8192x256] fp32
    bf16*  CATh  = (bf16*)QKV;                  // cross FF: [8192x256] bf16
    bf16*  Hh    = (bf16*)(base + 8552448 + 4194304);  // FF hidden, bf16 (<=8 MB)

    int NS = 1;
    if (ws_size >= 34800640ull + 4ull * 4718592ull) NS = 4;
    else if (ws_size >= 34800640ull + 2ull * 4718592ull) NS = 2;

    const int NTOK = B_ * T_ * N_;  // 8192

    // Weight prep
    k_pack<<<dim3((540672 + 255) / 256), dim3(256), 0, stream>>>(
        enc_qkv_W, enc_out_W, enc_ff_W1, enc_ff_W2, ca_Wq, ca_Wk, ca_Wv, ca_Wo,
        ca_ff_W1, ca_ff_W2, mlp_W2, Wpk);
    k_bpack<<<dim3(1), dim3(256), 0, stream>>>(ca_bk, ca_bv, bpk);
    k_tobf<<<dim3(4096), dim3(256), 0, stream>>>(semb, sembh, 1048576);

    // Residual features + token MLP
    k_b1<<<dim3((B_ * (T_ - 1) + 63) / 64), dim3(64), 0, stream>>>(
        vs, r5, A55, bl_bias, nl_W1, nl_b1, nl_W2, nl_b2, b1w);
    k_resid<<<dim3(NTOK / 64), dim3(64), 0, stream>>>(vs, b1w, resid);
    k_mlp1<<<dim3(NTOK), dim3(128), 0, stream>>>(resid, mlp_W1, mlp_b1, (bf16*)X1h);
    // reuse X1h as H1h scratch (X1h proper is written later)
    k_gemm<<<dim3(1024), dim3(256), 0, stream>>>(
        (bf16*)X1h, Wpk + 524288, mlp_b2, OF, nullptr, NTOK, 128, 128, 0);
    k_mlp2<<<dim3(NTOK), dim3(128), 0, stream>>>(OF, mlp_ln_g, mlp_ln_b, X0, X0h);

    // Encoder layers
    for (int i = 0; i < LENC_; i++) {
        k_gemm<<<dim3(3072), dim3(256), 0, stream>>>(
            X0h, Wpk + i * 49152, enc_qkv_b + i * 384, QKV, nullptr, NTOK, 384, 128, 0);
        k_fattn<<<dim3(128), dim3(256), 0, stream>>>(
            QKV, QKV, ATTh, part, 256, 1, 1, 0);
        k_gemm<<<dim3(1024), dim3(256), 0, stream>>>(
            ATTh, Wpk + 98304 + i * 16384, enc_out_b + i * 128, OF, nullptr,
            NTOK, 128, 128, 0);
        k_ln_res<<<dim3(NTOK), dim3(128), 0, stream>>>(
            X0, OF, enc_ln1_g + i * 128, enc_ln1_b + i * 128, X1, X1h, 128);
        k_gemm<<<dim3(2048), dim3(256), 0, stream>>>(
            X1h, Wpk + 131072 + i * 32768, enc_ff_b1 + i * 256, nullptr, Hh,
            NTOK, 256, 128, 1);
        k_gemm<<<dim3(1024), dim3(256), 0, stream>>>(
            Hh, Wpk + 196608 + i * 32768, enc_ff_b2 + i * 128, OF, nullptr,
            NTOK, 128, 256, 0);
        k_ln_res<<<dim3(NTOK), dim3(128), 0, stream>>>(
            X1, OF, enc_ln2_g + i * 128, enc_ln2_b + i * 128, X0, X0h, 128);
    }

    // Cross-attention
    k_gemm<<<dim3(1024), dim3(256), 0, stream>>>(
        sembh, Wpk + 262144, ca_bq, Qc, nullptr, NTOK, 128, 128, 0);
    k_gemm<<<dim3(2048), dim3(256), 0, stream>>>(
        X0h, Wpk + 278528, bpk, KVb, nullptr, NTOK, 256, 128, 0);
    k_fattn<<<dim3(16 * 8 * NS), dim3(256), 0, stream>>>(
        Qc, KVb, ATTh, part, 2048, 8, NS, 1);
    if (NS > 1)
        k_comb<<<dim3(128), dim3(256), 0, stream>>>(part, ATTh, NS);
    k_gemm<<<dim3(1024), dim3(256), 0, stream>>>(
        ATTh, Wpk + 311296, ca_bo, OF, nullptr, NTOK, 128, 128, 0);
    k_ln_res<<<dim3(NTOK), dim3(128), 0, stream>>>(
        semb, OF, ca_ln1_g, ca_ln1_b, X1, CATh, 256);  // X1 = s1; CAT[:, :128]
    k_cat<<<dim3(4096), dim3(256), 0, stream>>>(X0h, CATh);
    k_gemm<<<dim3(4096), dim3(256), 0, stream>>>(
        CATh, Wpk + 327680, ca_ff_b1, nullptr, Hh, NTOK, 512, 256, 1);
    k_gemm<<<dim3(1024), dim3(256), 0, stream>>>(
        Hh, Wpk + 458752, ca_ff_b2, OF, nullptr, NTOK, 128, 512, 0);
    k_ln_res<<<dim3(NTOK), dim3(128), 0, stream>>>(
        X1, OF, ca_ln2_g, ca_ln2_b, out, nullptr, 128);
}

// Round 4
// 485.839 us; speedup vs baseline: 10.5832x; 1.6053x over previous
//
#include <hip/hip_runtime.h>
#include <math.h>

// Problem constants
#define B_ 4
#define T_ 256
#define N_ 8
#define D_ 128
#define NH_ 4
#define HD_ 32
#define LENC_ 2
#define MLPH_ 32
#define NL_SCALE_ 0.1f

typedef __bf16 bf16;
typedef __attribute__((ext_vector_type(8))) __bf16 bf16x8;
typedef __attribute__((ext_vector_type(4))) float f32x4;

__device__ __forceinline__ float gelu_f(float x) {
    return 0.5f * x * (1.0f + erff(x * 0.7071067811865476f));
}

// Power-of-2 blockDim tree reduction. All threads must call.
__device__ __forceinline__ float block_sum(float v, float* scratch) {
    int tid = threadIdx.x;
    scratch[tid] = v;
    __syncthreads();
    for (int s = blockDim.x >> 1; s > 0; s >>= 1) {
        if (tid < s) scratch[tid] += scratch[tid + s];
        __syncthreads();
    }
    float r = scratch[0];
    __syncthreads();
    return r;
}

// ---------------------------------------------------------------------------
// Weight pack: fp32 -> bf16, all projection weights into one buffer.
__global__ void k_pack(const float* __restrict__ eqkvW, const float* __restrict__ eoutW,
                       const float* __restrict__ eff1, const float* __restrict__ eff2,
                       const float* __restrict__ wq, const float* __restrict__ wk,
                       const float* __restrict__ wv, const float* __restrict__ wo,
                       const float* __restrict__ cff1, const float* __restrict__ cff2,
                       const float* __restrict__ mlpW2, bf16* __restrict__ dst) {
    int i = blockIdx.x * 256 + threadIdx.x;
    if (i >= 540672) return;
    const float* src; int off;
    if      (i < 98304)  { src = eqkvW; off = 0; }
    else if (i < 131072) { src = eoutW; off = 98304; }
    else if (i < 196608) { src = eff1;  off = 131072; }
    else if (i < 262144) { src = eff2;  off = 196608; }
    else if (i < 278528) { src = wq;    off = 262144; }
    else if (i < 294912) { src = wk;    off = 278528; }
    else if (i < 311296) { src = wv;    off = 294912; }
    else if (i < 327680) { src = wo;    off = 311296; }
    else if (i < 458752) { src = cff1;  off = 327680; }
    else if (i < 524288) { src = cff2;  off = 458752; }
    else                 { src = mlpW2; off = 524288; }
    dst[i] = (bf16)src[i - off];
}

// bias pack for the cross KV gemm: [ca_bk ; ca_bv]
__global__ void k_bpack(const float* __restrict__ bk, const float* __restrict__ bv,
                        float* __restrict__ dst) {
    int t = threadIdx.x;
    dst[t] = (t < 128) ? bk[t] : bv[t - 128];
}

// fp32 -> bf16 flat convert (state_emb)
__global__ void k_tobf(const float* __restrict__ src, bf16* __restrict__ dst, int n) {
    int i = blockIdx.x * 256 + threadIdx.x;
    if (i < n) dst[i] = (bf16)src[i];
}

// ---------------------------------------------------------------------------
// K1: b1[b,t,m], t in [0,T-1)
__global__ void k_b1(const float* __restrict__ vs, const float* __restrict__ r5,
                     const float* __restrict__ A55, const float* __restrict__ bl_bias,
                     const float* __restrict__ nlW1, const float* __restrict__ nlb1,
                     const float* __restrict__ nlW2, const float* __restrict__ nlb2,
                     float* __restrict__ b1w) {
    int idx = blockIdx.x * blockDim.x + threadIdx.x;
    if (idx >= B_ * (T_ - 1)) return;
    int b = idx / (T_ - 1), t = idx % (T_ - 1);
    float x[N_];
    for (int n = 0; n < N_; n++) x[n] = vs[(b * T_ + t) * N_ + n];
    float h[MLPH_];
    for (int j = 0; j < MLPH_; j++) {
        float a = nlb1[j];
        for (int n = 0; n < N_; n++) a += x[n] * nlW1[j * N_ + n];
        h[j] = gelu_f(a);
    }
    for (int m = 0; m < N_; m++) {
        float lin = r5[m];
        for (int n = 0; n < N_; n++) lin += x[n] * A55[m * N_ + n];
        float nl = nlb2[m];
        for (int j = 0; j < MLPH_; j++) nl += h[j] * nlW2[m * MLPH_ + j];
        b1w[idx * N_ + m] = lin + NL_SCALE_ * nl + bl_bias[m];
    }
}

// ---------------------------------------------------------------------------
// K2: residuals[b,t,n,si] for SCALES = {1,2,3,5}
__global__ void k_resid(const float* __restrict__ vs, const float* __restrict__ b1w,
                        float* __restrict__ resid) {
    int idx = blockIdx.x * blockDim.x + threadIdx.x;
    if (idx >= B_ * T_ * N_) return;
    int b = idx / (T_ * N_);
    int t = (idx / N_) % T_;
    int n = idx % N_;
    const int SC[4] = {1, 2, 3, 5};
    float lx0 = logf(fmaxf(vs[(b * T_ + t) * N_ + n], 1e-6f));
    for (int si = 0; si < 4; si++) {
        int k = SC[si];
        float r = 0.0f;
        if (t < T_ - k) {
            float lx1 = logf(fmaxf(vs[(b * T_ + t + k) * N_ + n], 1e-6f));
            float a = lx1 - lx0;
            float cmin = -2.5f * (float)k, cmax = 2.0f * (float)k;
            a = fminf(fmaxf(a, cmin), cmax);
            float bk = 0.0f;
            for (int i = 0; i < k; i++) bk += b1w[(b * (T_ - 1) + t + i) * N_ + n];
            r = a - bk;
        }
        resid[idx * 4 + si] = r;
    }
}

// ---------------------------------------------------------------------------
// K3a: per-token MLP layer1 (16 -> 128, gelu), output bf16 in (b,t,n) order.
__global__ void k_mlp1(const float* __restrict__ resid, const float* __restrict__ W1,
                       const float* __restrict__ b1, bf16* __restrict__ H1h) {
    int tok = blockIdx.x;                  // b*2048 + t*8 + n
    int d = threadIdx.x;                   // 128
    int b = tok >> 11, t = (tok >> 3) & 255, n = tok & 7;
    __shared__ float f[16];
    if (d < 16) {
        int g = d >> 2, si = d & 3;
        f[d] = (t - g >= 0) ? resid[((b * T_ + (t - g)) * N_ + n) * 4 + si] : 0.0f;
    }
    __syncthreads();
    float a = b1[d];
    const float* w = W1 + d * 16;
#pragma unroll
    for (int c = 0; c < 16; c++) a += f[c] * w[c];
    H1h[(size_t)tok * 128 + d] = (bf16)gelu_f(a);
}

// K3b: gelu(OF) -> LN -> +PE -> write X0 fp32 + bf16, transposed to xt order.
__global__ void k_mlp2(const float* __restrict__ OF, const float* __restrict__ g,
                       const float* __restrict__ be, float* __restrict__ X0,
                       bf16* __restrict__ X0h) {
    int tok = blockIdx.x;
    int d = threadIdx.x;
    int b = tok >> 11, t = (tok >> 3) & 255, n = tok & 7;
    __shared__ float scratch[128];
    float v = gelu_f(OF[(size_t)tok * 128 + d]);
    float mean = block_sum(v, scratch) * (1.0f / 128.0f);
    float dv = v - mean;
    float var = block_sum(dv * dv, scratch) * (1.0f / 128.0f);
    float y = dv * rsqrtf(var + 1e-5f) * g[d] + be[d];
    int j = d >> 1;
    float freq = expf((float)(2 * j) * (-9.210340371976184f / 128.0f));
    float ang = (float)t * freq;
    y += (d & 1) ? cosf(ang) : sinf(ang);
    size_t r = ((size_t)(b * 8 + n) * 256 + t) * 128 + d;
    X0[r] = y;
    X0h[r] = (bf16)y;
}

// ---------------------------------------------------------------------------
// MFMA GEMM: C[M x N] = act(A @ W^T + bias). A bf16 [MxK] rowmajor,
// W bf16 [NxK] rowmajor. One 16x16 C tile per wave; 4 waves/block.
// mode 0: row-major write (Cf fp32 / Ch bf16).
// mode 1 (enc QKV, N=384): scatter to Qh/Kh [sh][256][32], Vth [sh][32][256].
// mode 2 (cross Q, N=128): scatter to Qh [sh][2048][32].
// mode 3 (cross KV, N=256): scatter K->Kh [sh][2048][32], V->Vth [sh][32][2048],
//         with l = t*8+n remap from xt row order.
__global__ __launch_bounds__(256) void k_gemm(
    const bf16* __restrict__ A, const bf16* __restrict__ W,
    const float* __restrict__ bias, float* __restrict__ Cf,
    bf16* __restrict__ Ch, bf16* __restrict__ dq, bf16* __restrict__ dk,
    bf16* __restrict__ dvv, int M, int N, int K, int act, int mode) {
    int lane = threadIdx.x & 63;
    int wv = threadIdx.x >> 6;
    int wtile = blockIdx.x * 4 + wv;
    int nN = N >> 4;
    int tn = wtile % nN, tm = wtile / nN;
    if (tm >= (M >> 4)) return;
    int mrow = tm * 16 + (lane & 15);
    int nrow = tn * 16 + (lane & 15);
    int g = lane >> 4;
    const bf16x8* Ap = (const bf16x8*)(A + (size_t)mrow * K) + g;
    const bf16x8* Wp = (const bf16x8*)(W + (size_t)nrow * K) + g;
    f32x4 acc = {0.0f, 0.0f, 0.0f, 0.0f};
    int nk = K >> 5;
    for (int k = 0; k < nk; k++) {
        bf16x8 av = Ap[k * 4];
        bf16x8 bv8 = Wp[k * 4];
        acc = __builtin_amdgcn_mfma_f32_16x16x32_bf16(av, bv8, acc, 0, 0, 0);
    }
    int col = tn * 16 + (lane & 15);
    int row0 = tm * 16 + g * 4;
    float bvv = bias[col];
#pragma unroll
    for (int i = 0; i < 4; i++) {
        float v = acc[i] + bvv;
        if (act) v = gelu_f(v);
        int row = row0 + i;
        if (mode == 0) {
            if (Cf) Cf[(size_t)row * N + col] = v;
            if (Ch) Ch[(size_t)row * N + col] = (bf16)v;
        } else if (mode == 1) {
            int s = row >> 8, t = row & 255;
            int h = (col >> 5) & 3, d = col & 31;
            int sh = s * 4 + h;
            if (col < 128)      dq[((size_t)sh * 256 + t) * 32 + d] = (bf16)v;
            else if (col < 256) dk[((size_t)sh * 256 + t) * 32 + d] = (bf16)v;
            else                dvv[((size_t)sh * 32 + d) * 256 + t] = (bf16)v;
        } else if (mode == 2) {
            int b = row >> 11, ll = row & 2047;
            int h = col >> 5, d = col & 31;
            dq[((size_t)(b * 4 + h) * 2048 + ll) * 32 + d] = (bf16)v;
        } else {
            int b = row >> 11, n = (row >> 8) & 7, t = row & 255;
            int ll = t * 8 + n;
            int h = (col >> 5) & 3, d = col & 31;
            if (col < 128) dk[((size_t)(b * 4 + h) * 2048 + ll) * 32 + d] = (bf16)v;
            else           dvv[((size_t)(b * 4 + h) * 32 + d) * 2048 + ll] = (bf16)v;
        }
    }
}

// ---------------------------------------------------------------------------
// MFMA flash attention. Wave = 16 queries; key tiles of 32; no running max
// (scores bounded << 88, exp(s) safe in fp32). grid = NSH * (Lq/64).
// Qh [sh][Lq][32], Kh [sh][Lk][32], Vth [sh][32][Lk] (bf16, V transposed).
// Output ATTh[((sh>>2)*Lq + q)*128 + (sh&3)*32 + d] (bf16).
__global__ __launch_bounds__(256) void k_mattn(
    const bf16* __restrict__ Qh, const bf16* __restrict__ Kh,
    const bf16* __restrict__ Vth, bf16* __restrict__ ATTh, int Lq, int Lk) {
    int nqb = Lq >> 6;
    int qblk = blockIdx.x % nqb;
    int sh = blockIdx.x / nqb;
    int wv = threadIdx.x >> 6;
    int lane = threadIdx.x & 63;
    int c = lane & 15, g = lane >> 4;
    int q0 = qblk * 64 + wv * 16;

    __shared__ __align__(16) bf16 P_lds[2][4][16][40];  // +8 pad: conflict-free b128

    bf16x8 aq = *(const bf16x8*)(Qh + ((size_t)sh * Lq + q0 + c) * 32 + g * 8);
    const bf16* Kbase = Kh + (size_t)sh * Lk * 32;
    const bf16* Vbase = Vth + (size_t)sh * 32 * Lk;

    f32x4 o0 = {0, 0, 0, 0}, o1 = {0, 0, 0, 0};
    float l[4] = {0, 0, 0, 0};
    const float scale = 0.17677669529663687f;  // 1/sqrt(32)
    const f32x4 zero = {0, 0, 0, 0};

    int buf = 0;
    for (int k0 = 0; k0 < Lk; k0 += 32, buf ^= 1) {
        bf16x8 bk0 = *(const bf16x8*)(Kbase + (size_t)(k0 + c) * 32 + g * 8);
        bf16x8 bk1 = *(const bf16x8*)(Kbase + (size_t)(k0 + 16 + c) * 32 + g * 8);
        f32x4 s0 = __builtin_amdgcn_mfma_f32_16x16x32_bf16(aq, bk0, zero, 0, 0, 0);
        f32x4 s1 = __builtin_amdgcn_mfma_f32_16x16x32_bf16(aq, bk1, zero, 0, 0, 0);
        // p = exp(s*scale); accumulate per-lane partial row sums (rows q=g*4+r)
#pragma unroll
        for (int r = 0; r < 4; r++) {
            float e0 = __expf(s0[r] * scale);
            float e1 = __expf(s1[r] * scale);
            l[r] += e0 + e1;
            P_lds[buf][wv][g * 4 + r][c] = (bf16)e0;
            P_lds[buf][wv][g * 4 + r][16 + c] = (bf16)e1;
        }
        __syncthreads();
        bf16x8 ap = *(const bf16x8*)&P_lds[buf][wv][c][g * 8];
        bf16x8 bv0 = *(const bf16x8*)(Vbase + (size_t)c * Lk + k0 + g * 8);
        bf16x8 bv1 = *(const bf16x8*)(Vbase + (size_t)(16 + c) * Lk + k0 + g * 8);
        o0 = __builtin_amdgcn_mfma_f32_16x16x32_bf16(ap, bv0, o0, 0, 0, 0);
        o1 = __builtin_amdgcn_mfma_f32_16x16x32_bf16(ap, bv1, o1, 0, 0, 0);
    }
    // reduce l across the 16 lanes sharing g (keys split over lane&15)
#pragma unroll
    for (int r = 0; r < 4; r++) {
        float s = l[r];
        s += __shfl_xor(s, 1);
        s += __shfl_xor(s, 2);
        s += __shfl_xor(s, 4);
        s += __shfl_xor(s, 8);
        l[r] = 1.0f / s;
    }
    int h = sh & 3, sb = sh >> 2;
#pragma unroll
    for (int r = 0; r < 4; r++) {
        size_t row = (size_t)sb * Lq + q0 + g * 4 + r;
        ATTh[row * 128 + h * 32 + c] = (bf16)(o0[r] * l[r]);
        ATTh[row * 128 + h * 32 + 16 + c] = (bf16)(o1[r] * l[r]);
    }
}

// ---------------------------------------------------------------------------
// Residual + LN: y = LN(xin + delta)*g + be. Writes fp32 (if xf) and bf16
// (if xh, with row stride hstride — used to write into the CAT buffer).
__global__ void k_ln_res(const float* __restrict__ xin, const float* __restrict__ delta,
                         const float* __restrict__ g, const float* __restrict__ be,
                         float* __restrict__ xf, bf16* __restrict__ xh, int hstride) {
    int tok = blockIdx.x;
    int d = threadIdx.x;
    __shared__ float scratch[128];
    float v = xin[(size_t)tok * 128 + d] + delta[(size_t)tok * 128 + d];
    float mean = block_sum(v, scratch) * (1.0f / 128.0f);
    float dv = v - mean;
    float var = block_sum(dv * dv, scratch) * (1.0f / 128.0f);
    float y = dv * rsqrtf(var + 1e-5f) * g[d] + be[d];
    if (xf) xf[(size_t)tok * 128 + d] = y;
    if (xh) xh[(size_t)tok * hstride + d] = (bf16)y;
}

// Fill CAT[:,128:256] from encoder output X0h (xt order -> (b,t,n) order).
__global__ void k_cat(const bf16* __restrict__ X0h, bf16* __restrict__ CATh) {
    int i = blockIdx.x * 256 + threadIdx.x;   // over 1048576
    if (i >= 1048576) return;
    int tok = i >> 7, d = i & 127;
    int b = tok >> 11, t = (tok >> 3) & 255, n = tok & 7;
    CATh[(size_t)tok * 256 + 128 + d] = X0h[((size_t)(b * 8 + n) * 256 + t) * 128 + d];
}

// ---------------------------------------------------------------------------
extern "C" void kernel_launch(void* const* d_in, const int* in_sizes, int n_in,
                              void* d_out, int out_size, void* d_ws, size_t ws_size,
                              hipStream_t stream) {
    const float* vs       = (const float*)d_in[0];
    const float* semb     = (const float*)d_in[1];
    const float* r5       = (const float*)d_in[2];
    const float* A55      = (const float*)d_in[3];
    const float* bl_bias  = (const float*)d_in[4];
    const float* nl_W1    = (const float*)d_in[5];
    const float* nl_b1    = (const float*)d_in[6];
    const float* nl_W2    = (const float*)d_in[7];
    const float* nl_b2    = (const float*)d_in[8];
    const float* mlp_W1   = (const float*)d_in[9];
    const float* mlp_b1   = (const float*)d_in[10];
    const float* mlp_W2   = (const float*)d_in[11];
    const float* mlp_b2   = (const float*)d_in[12];
    const float* mlp_ln_g = (const float*)d_in[13];
    const float* mlp_ln_b = (const float*)d_in[14];
    const float* enc_qkv_W = (const float*)d_in[15];
    const float* enc_qkv_b = (const float*)d_in[16];
    const float* enc_out_W = (const float*)d_in[17];
    const float* enc_out_b = (const float*)d_in[18];
    const float* enc_ln1_g = (const float*)d_in[19];
    const float* enc_ln1_b = (const float*)d_in[20];
    const float* enc_ff_W1 = (const float*)d_in[21];
    const float* enc_ff_b1 = (const float*)d_in[22];
    const float* enc_ff_W2 = (const float*)d_in[23];
    const float* enc_ff_b2 = (const float*)d_in[24];
    const float* enc_ln2_g = (const float*)d_in[25];
    const float* enc_ln2_b = (const float*)d_in[26];
    const float* ca_Wq = (const float*)d_in[27];
    const float* ca_bq = (const float*)d_in[28];
    const float* ca_Wk = (const float*)d_in[29];
    const float* ca_bk = (const float*)d_in[30];
    const float* ca_Wv = (const float*)d_in[31];
    const float* ca_bv = (const float*)d_in[32];
    const float* ca_Wo = (const float*)d_in[33];
    const float* ca_bo = (const float*)d_in[34];
    const float* ca_ln1_g = (const float*)d_in[35];
    const float* ca_ln1_b = (const float*)d_in[36];
    const float* ca_ff_W1 = (const float*)d_in[37];
    const float* ca_ff_b1 = (const float*)d_in[38];
    const float* ca_ff_W2 = (const float*)d_in[39];
    const float* ca_ff_b2 = (const float*)d_in[40];
    const float* ca_ln2_g = (const float*)d_in[41];
    const float* ca_ln2_b = (const float*)d_in[42];
    float* out = (float*)d_out;

    // Workspace layout (byte offsets, 256-aligned)
    char* base = (char*)d_ws;
    float* b1w   = (float*)(base + 0);          //  32 KB
    float* resid = (float*)(base + 32768);      // 128 KB
    float* X0    = (float*)(base + 163840);     //   4 MB
    float* X1    = (float*)(base + 4358144);    //   4 MB
    char*  QKVr  = base + 8552448;              //  12 MB region
    float* OF    = (float*)(base + 21135360);   //   4 MB
    bf16*  Wpk   = (bf16*) (base + 25329664);   // 1.03 MB
    float* bpk   = (float*)(base + 26411008);   //   1 KB
    bf16*  X0h   = (bf16*) (base + 26412032);   //   2 MB
    bf16*  X1h   = (bf16*) (base + 28509184);   //   2 MB
    bf16*  sembh = (bf16*) (base + 30606336);   //   2 MB
    bf16*  ATTh  = (bf16*) (base + 32703488);   //   2 MB
    bf16*  Qh    = (bf16*)QKVr;                 //   2 MB
    bf16*  Kh    = (bf16*)(QKVr + 2097152);     //   2 MB
    bf16*  Vth   = (bf16*)(QKVr + 4194304);     //   2 MB
    bf16*  CATh  = (bf16*)QKVr;                 //   4 MB (after attn done)
    bf16*  Hh    = (bf16*)(QKVr + 4194304);     //  <=8 MB (after attn done)

    const int NTOK = B_ * T_ * N_;  // 8192

    // Weight prep
    k_pack<<<dim3((540672 + 255) / 256), dim3(256), 0, stream>>>(
        enc_qkv_W, enc_out_W, enc_ff_W1, enc_ff_W2, ca_Wq, ca_Wk, ca_Wv, ca_Wo,
        ca_ff_W1, ca_ff_W2, mlp_W1 ? mlp_W2 : mlp_W2, Wpk);
    k_bpack<<<dim3(1), dim3(256), 0, stream>>>(ca_bk, ca_bv, bpk);
    k_tobf<<<dim3(4096), dim3(256), 0, stream>>>(semb, sembh, 1048576);

    // Residual features + token MLP
    k_b1<<<dim3((B_ * (T_ - 1) + 63) / 64), dim3(64), 0, stream>>>(
        vs, r5, A55, bl_bias, nl_W1, nl_b1, nl_W2, nl_b2, b1w);
    k_resid<<<dim3(NTOK / 64), dim3(64), 0, stream>>>(vs, b1w, resid);
    k_mlp1<<<dim3(NTOK), dim3(128), 0, stream>>>(resid, mlp_W1, mlp_b1, (bf16*)X1h);
    k_gemm<<<dim3(1024), dim3(256), 0, stream>>>(
        (bf16*)X1h, Wpk + 524288, mlp_b2, OF, nullptr, nullptr, nullptr, nullptr,
        NTOK, 128, 128, 0, 0);
    k_mlp2<<<dim3(NTOK), dim3(128), 0, stream>>>(OF, mlp_ln_g, mlp_ln_b, X0, X0h);

    // Encoder layers
    for (int i = 0; i < LENC_; i++) {
        k_gemm<<<dim3(3072), dim3(256), 0, stream>>>(
            X0h, Wpk + i * 49152, enc_qkv_b + i * 384, nullptr, nullptr,
            Qh, Kh, Vth, NTOK, 384, 128, 0, 1);
        k_mattn<<<dim3(128 * 4), dim3(256), 0, stream>>>(Qh, Kh, Vth, ATTh, 256, 256);
        k_gemm<<<dim3(1024), dim3(256), 0, stream>>>(
            ATTh, Wpk + 98304 + i * 16384, enc_out_b + i * 128, OF, nullptr,
            nullptr, nullptr, nullptr, NTOK, 128, 128, 0, 0);
        k_ln_res<<<dim3(NTOK), dim3(128), 0, stream>>>(
            X0, OF, enc_ln1_g + i * 128, enc_ln1_b + i * 128, X1, X1h, 128);
        k_gemm<<<dim3(2048), dim3(256), 0, stream>>>(
            X1h, Wpk + 131072 + i * 32768, enc_ff_b1 + i * 256, nullptr, Hh,
            nullptr, nullptr, nullptr, NTOK, 256, 128, 1, 0);
        k_gemm<<<dim3(1024), dim3(256), 0, stream>>>(
            Hh, Wpk + 196608 + i * 32768, enc_ff_b2 + i * 128, OF, nullptr,
            nullptr, nullptr, nullptr, NTOK, 128, 256, 0, 0);
        k_ln_res<<<dim3(NTOK), dim3(128), 0, stream>>>(
            X1, OF, enc_ln2_g + i * 128, enc_ln2_b + i * 128, X0, X0h, 128);
    }

    // Cross-attention (NSH = 16, Lq = Lk = 2048)
    k_gemm<<<dim3(1024), dim3(256), 0, stream>>>(
        sembh, Wpk + 262144, ca_bq, nullptr, nullptr, Qh, nullptr, nullptr,
        NTOK, 128, 128, 0, 2);
    k_gemm<<<dim3(2048), dim3(256), 0, stream>>>(
        X0h, Wpk + 278528, bpk, nullptr, nullptr, nullptr, Kh, Vth,
        NTOK, 256, 128, 0, 3);
    k_mattn<<<dim3(16 * 32), dim3(256), 0, stream>>>(Qh, Kh, Vth, ATTh, 2048, 2048);
    k_gemm<<<dim3(1024), dim3(256), 0, stream>>>(
        ATTh, Wpk + 311296, ca_bo, OF, nullptr, nullptr, nullptr, nullptr,
        NTOK, 128, 128, 0, 0);
    k_ln_res<<<dim3(NTOK), dim3(128), 0, stream>>>(
        semb, OF, ca_ln1_g, ca_ln1_b, X1, CATh, 256);  // X1 = s1; CAT[:, :128]
    k_cat<<<dim3(4096), dim3(256), 0, stream>>>(X0h, CATh);
    k_gemm<<<dim3(4096), dim3(256), 0, stream>>>(
        CATh, Wpk + 327680, ca_ff_b1, nullptr, Hh, nullptr, nullptr, nullptr,
        NTOK, 512, 256, 1, 0);
    k_gemm<<<dim3(1024), dim3(256), 0, stream>>>(
        Hh, Wpk + 458752, ca_ff_b2, OF, nullptr, nullptr, nullptr, nullptr,
        NTOK, 128, 512, 0, 0);
    k_ln_res<<<dim3(NTOK), dim3(128), 0, stream>>>(
        X1, OF, ca_ln2_g, ca_ln2_b, out, nullptr, 128);
}

// Round 5
// 481.482 us; speedup vs baseline: 10.6789x; 1.0090x over previous
//
#include <hip/hip_runtime.h>
#include <math.h>

// Problem constants
#define B_ 4
#define T_ 256
#define N_ 8
#define D_ 128
#define NH_ 4
#define HD_ 32
#define LENC_ 2
#define MLPH_ 32
#define NL_SCALE_ 0.1f

typedef __bf16 bf16;
typedef __attribute__((ext_vector_type(2))) __bf16 bf16x2;
typedef __attribute__((ext_vector_type(8))) __bf16 bf16x8;
typedef __attribute__((ext_vector_type(4))) float f32x4;

__device__ __forceinline__ float gelu_f(float x) {
    return 0.5f * x * (1.0f + erff(x * 0.7071067811865476f));
}

// Power-of-2 blockDim tree reduction. All threads must call.
__device__ __forceinline__ float block_sum(float v, float* scratch) {
    int tid = threadIdx.x;
    scratch[tid] = v;
    __syncthreads();
    for (int s = blockDim.x >> 1; s > 0; s >>= 1) {
        if (tid < s) scratch[tid] += scratch[tid + s];
        __syncthreads();
    }
    float r = scratch[0];
    __syncthreads();
    return r;
}

// ---------------------------------------------------------------------------
// Merged prep: weight pack fp32->bf16, state_emb->bf16, bias pack.
__global__ void k_prep(const float* __restrict__ eqkvW, const float* __restrict__ eoutW,
                       const float* __restrict__ eff1, const float* __restrict__ eff2,
                       const float* __restrict__ wq, const float* __restrict__ wk,
                       const float* __restrict__ wv, const float* __restrict__ wo,
                       const float* __restrict__ cff1, const float* __restrict__ cff2,
                       const float* __restrict__ mlpW2, const float* __restrict__ semb,
                       const float* __restrict__ bk, const float* __restrict__ bv,
                       bf16* __restrict__ Wpk, bf16* __restrict__ sembh,
                       float* __restrict__ bpk) {
    int i = blockIdx.x * 256 + threadIdx.x;
    if (i < 540672) {
        const float* src; int off;
        if      (i < 98304)  { src = eqkvW; off = 0; }
        else if (i < 131072) { src = eoutW; off = 98304; }
        else if (i < 196608) { src = eff1;  off = 131072; }
        else if (i < 262144) { src = eff2;  off = 196608; }
        else if (i < 278528) { src = wq;    off = 262144; }
        else if (i < 294912) { src = wk;    off = 278528; }
        else if (i < 311296) { src = wv;    off = 294912; }
        else if (i < 327680) { src = wo;    off = 311296; }
        else if (i < 458752) { src = cff1;  off = 327680; }
        else if (i < 524288) { src = cff2;  off = 458752; }
        else                 { src = mlpW2; off = 524288; }
        Wpk[i] = (bf16)src[i - off];
    } else if (i < 540672 + 1048576) {
        int j = i - 540672;
        sembh[j] = (bf16)semb[j];
    } else if (i < 540672 + 1048576 + 256) {
        int t = i - 540672 - 1048576;
        bpk[t] = (t < 128) ? bk[t] : bv[t - 128];
    }
}

// ---------------------------------------------------------------------------
// K1: b1[b,t,m], t in [0,T-1)
__global__ void k_b1(const float* __restrict__ vs, const float* __restrict__ r5,
                     const float* __restrict__ A55, const float* __restrict__ bl_bias,
                     const float* __restrict__ nlW1, const float* __restrict__ nlb1,
                     const float* __restrict__ nlW2, const float* __restrict__ nlb2,
                     float* __restrict__ b1w) {
    int idx = blockIdx.x * blockDim.x + threadIdx.x;
    if (idx >= B_ * (T_ - 1)) return;
    int b = idx / (T_ - 1), t = idx % (T_ - 1);
    float x[N_];
    for (int n = 0; n < N_; n++) x[n] = vs[(b * T_ + t) * N_ + n];
    float h[MLPH_];
    for (int j = 0; j < MLPH_; j++) {
        float a = nlb1[j];
        for (int n = 0; n < N_; n++) a += x[n] * nlW1[j * N_ + n];
        h[j] = gelu_f(a);
    }
    for (int m = 0; m < N_; m++) {
        float lin = r5[m];
        for (int n = 0; n < N_; n++) lin += x[n] * A55[m * N_ + n];
        float nl = nlb2[m];
        for (int j = 0; j < MLPH_; j++) nl += h[j] * nlW2[m * MLPH_ + j];
        b1w[idx * N_ + m] = lin + NL_SCALE_ * nl + bl_bias[m];
    }
}

// ---------------------------------------------------------------------------
// K2: residuals[b,t,n,si] for SCALES = {1,2,3,5}
__global__ void k_resid(const float* __restrict__ vs, const float* __restrict__ b1w,
                        float* __restrict__ resid) {
    int idx = blockIdx.x * blockDim.x + threadIdx.x;
    if (idx >= B_ * T_ * N_) return;
    int b = idx / (T_ * N_);
    int t = (idx / N_) % T_;
    int n = idx % N_;
    const int SC[4] = {1, 2, 3, 5};
    float lx0 = logf(fmaxf(vs[(b * T_ + t) * N_ + n], 1e-6f));
    for (int si = 0; si < 4; si++) {
        int k = SC[si];
        float r = 0.0f;
        if (t < T_ - k) {
            float lx1 = logf(fmaxf(vs[(b * T_ + t + k) * N_ + n], 1e-6f));
            float a = lx1 - lx0;
            float cmin = -2.5f * (float)k, cmax = 2.0f * (float)k;
            a = fminf(fmaxf(a, cmin), cmax);
            float bk = 0.0f;
            for (int i = 0; i < k; i++) bk += b1w[(b * (T_ - 1) + t + i) * N_ + n];
            r = a - bk;
        }
        resid[idx * 4 + si] = r;
    }
}

// ---------------------------------------------------------------------------
// K3a: per-token MLP layer1 (16 -> 128, gelu), output bf16 in (b,t,n) order.
__global__ void k_mlp1(const float* __restrict__ resid, const float* __restrict__ W1,
                       const float* __restrict__ b1, bf16* __restrict__ H1h) {
    int tok = blockIdx.x;                  // b*2048 + t*8 + n
    int d = threadIdx.x;                   // 128
    int b = tok >> 11, t = (tok >> 3) & 255, n = tok & 7;
    __shared__ float f[16];
    if (d < 16) {
        int g = d >> 2, si = d & 3;
        f[d] = (t - g >= 0) ? resid[((b * T_ + (t - g)) * N_ + n) * 4 + si] : 0.0f;
    }
    __syncthreads();
    float a = b1[d];
    const float* w = W1 + d * 16;
#pragma unroll
    for (int c = 0; c < 16; c++) a += f[c] * w[c];
    H1h[(size_t)tok * 128 + d] = (bf16)gelu_f(a);
}

// K3b: gelu(OF) -> LN -> +PE -> write X0 fp32 + bf16, transposed to xt order.
__global__ void k_mlp2(const float* __restrict__ OF, const float* __restrict__ g,
                       const float* __restrict__ be, float* __restrict__ X0,
                       bf16* __restrict__ X0h) {
    int tok = blockIdx.x;
    int d = threadIdx.x;
    int b = tok >> 11, t = (tok >> 3) & 255, n = tok & 7;
    __shared__ float scratch[128];
    float v = gelu_f(OF[(size_t)tok * 128 + d]);
    float mean = block_sum(v, scratch) * (1.0f / 128.0f);
    float dv = v - mean;
    float var = block_sum(dv * dv, scratch) * (1.0f / 128.0f);
    float y = dv * rsqrtf(var + 1e-5f) * g[d] + be[d];
    int j = d >> 1;
    float freq = expf((float)(2 * j) * (-9.210340371976184f / 128.0f));
    float ang = (float)t * freq;
    y += (d & 1) ? cosf(ang) : sinf(ang);
    size_t r = ((size_t)(b * 8 + n) * 256 + t) * 128 + d;
    X0[r] = y;
    X0h[r] = (bf16)y;
}

// ---------------------------------------------------------------------------
// MFMA GEMM: C[M x N] = act(A @ W^T + bias). A bf16 [MxK] rowmajor,
// W bf16 [NxK] rowmajor. One 16x16 C tile per wave; 4 waves/block.
// mode 0: row-major write (Cf fp32 / Ch bf16).
// mode 1 (enc QKV, N=384): scatter to Qh/Kh [sh][256][32], Vth [sh][32][256].
// mode 2 (cross Q, N=128): scatter to Qh [sh][2048][32].
// mode 3 (cross KV, N=256): scatter K->Kh [sh][2048][32], V->Vth [sh][32][2048],
//         with l = t*8+n remap from xt row order.
__global__ __launch_bounds__(256) void k_gemm(
    const bf16* __restrict__ A, const bf16* __restrict__ W,
    const float* __restrict__ bias, float* __restrict__ Cf,
    bf16* __restrict__ Ch, bf16* __restrict__ dq, bf16* __restrict__ dk,
    bf16* __restrict__ dvv, int M, int N, int K, int act, int mode) {
    int lane = threadIdx.x & 63;
    int wv = threadIdx.x >> 6;
    int wtile = blockIdx.x * 4 + wv;
    int nN = N >> 4;
    int tn = wtile % nN, tm = wtile / nN;
    if (tm >= (M >> 4)) return;
    int mrow = tm * 16 + (lane & 15);
    int nrow = tn * 16 + (lane & 15);
    int g = lane >> 4;
    const bf16x8* Ap = (const bf16x8*)(A + (size_t)mrow * K) + g;
    const bf16x8* Wp = (const bf16x8*)(W + (size_t)nrow * K) + g;
    f32x4 acc = {0.0f, 0.0f, 0.0f, 0.0f};
    int nk = K >> 5;
    for (int k = 0; k < nk; k++) {
        bf16x8 av = Ap[k * 4];
        bf16x8 bv8 = Wp[k * 4];
        acc = __builtin_amdgcn_mfma_f32_16x16x32_bf16(av, bv8, acc, 0, 0, 0);
    }
    int col = tn * 16 + (lane & 15);
    int row0 = tm * 16 + g * 4;
    float bvv = bias[col];
#pragma unroll
    for (int i = 0; i < 4; i++) {
        float v = acc[i] + bvv;
        if (act) v = gelu_f(v);
        int row = row0 + i;
        if (mode == 0) {
            if (Cf) Cf[(size_t)row * N + col] = v;
            if (Ch) Ch[(size_t)row * N + col] = (bf16)v;
        } else if (mode == 1) {
            int s = row >> 8, t = row & 255;
            int h = (col >> 5) & 3, d = col & 31;
            int sh = s * 4 + h;
            if (col < 128)      dq[((size_t)sh * 256 + t) * 32 + d] = (bf16)v;
            else if (col < 256) dk[((size_t)sh * 256 + t) * 32 + d] = (bf16)v;
            else                dvv[((size_t)sh * 32 + d) * 256 + t] = (bf16)v;
        } else if (mode == 2) {
            int b = row >> 11, ll = row & 2047;
            int h = col >> 5, d = col & 31;
            dq[((size_t)(b * 4 + h) * 2048 + ll) * 32 + d] = (bf16)v;
        } else {
            int b = row >> 11, n = (row >> 8) & 7, t = row & 255;
            int ll = t * 8 + n;
            int h = (col >> 5) & 3, d = col & 31;
            if (col < 128) dk[((size_t)(b * 4 + h) * 2048 + ll) * 32 + d] = (bf16)v;
            else           dvv[((size_t)(b * 4 + h) * 32 + d) * 2048 + ll] = (bf16)v;
        }
    }
}

// ---------------------------------------------------------------------------
// MFMA flash attention v2: wave-private (no barriers), prefetched, packed
// LDS P writes. Wave = 16 queries; 32-key tiles with interleaved key loads
// (lane c handles keys 2c, 2c+1 so its two exp results pack into one dword).
// No running max (scores bounded << 88). grid = NSH * (Lq/64).
// Qh [sh][Lq][32], Kh [sh][Lk][32], Vth [sh][32][Lk] (bf16, V transposed).
// Output ATTh[((sh>>2)*Lq + q)*128 + (sh&3)*32 + d] (bf16).
__global__ __launch_bounds__(256) void k_mattn(
    const bf16* __restrict__ Qh, const bf16* __restrict__ Kh,
    const bf16* __restrict__ Vth, bf16* __restrict__ ATTh, int Lq, int Lk) {
    int nqb = Lq >> 6;
    int qblk = blockIdx.x % nqb;
    int sh = blockIdx.x / nqb;
    int wv = threadIdx.x >> 6;
    int lane = threadIdx.x & 63;
    int c = lane & 15, g = lane >> 4;
    int q0 = qblk * 64 + wv * 16;

    // P tile per wave, double-buffered; rows padded to 20 dwords (80B) so
    // b128 reads / b32 writes are <=2-way bank aliased (free).
    __shared__ __align__(16) bf16x2 P_lds[2][4][16][20];

    bf16x8 aq = *(const bf16x8*)(Qh + ((size_t)sh * Lq + q0 + c) * 32 + g * 8);
    const bf16* Kbase = Kh + (size_t)sh * Lk * 32;
    const bf16* Vbase = Vth + (size_t)sh * 32 * Lk;

    f32x4 o0 = {0, 0, 0, 0}, o1 = {0, 0, 0, 0};
    float l[4] = {0, 0, 0, 0};
    const float scale = 0.17677669529663687f;  // 1/sqrt(32)
    const f32x4 zero = {0, 0, 0, 0};

    int ntiles = Lk >> 5;
    // prefetch tile 0: keys 2c, 2c+1 (interleaved); V dims c, 16+c
    bf16x8 ka = *(const bf16x8*)(Kbase + (size_t)(2 * c) * 32 + g * 8);
    bf16x8 kb = *(const bf16x8*)(Kbase + (size_t)(2 * c + 1) * 32 + g * 8);
    bf16x8 va = *(const bf16x8*)(Vbase + (size_t)c * Lk + g * 8);
    bf16x8 vb = *(const bf16x8*)(Vbase + (size_t)(16 + c) * Lk + g * 8);

    for (int t = 0; t < ntiles; t++) {
        bf16x8 cka = ka, ckb = kb, cva = va, cvb = vb;
        int nk0 = ((t + 1 < ntiles) ? (t + 1) : t) << 5;
        ka = *(const bf16x8*)(Kbase + (size_t)(nk0 + 2 * c) * 32 + g * 8);
        kb = *(const bf16x8*)(Kbase + (size_t)(nk0 + 2 * c + 1) * 32 + g * 8);
        va = *(const bf16x8*)(Vbase + (size_t)c * Lk + nk0 + g * 8);
        vb = *(const bf16x8*)(Vbase + (size_t)(16 + c) * Lk + nk0 + g * 8);

        f32x4 s0 = __builtin_amdgcn_mfma_f32_16x16x32_bf16(aq, cka, zero, 0, 0, 0);
        f32x4 s1 = __builtin_amdgcn_mfma_f32_16x16x32_bf16(aq, ckb, zero, 0, 0, 0);
        int buf = t & 1;
#pragma unroll
        for (int r = 0; r < 4; r++) {
            float e0 = __expf(s0[r] * scale);   // score(q=g*4+r, key 2c)
            float e1 = __expf(s1[r] * scale);   // score(q=g*4+r, key 2c+1)
            l[r] += e0 + e1;
            bf16x2 pk; pk[0] = (bf16)e0; pk[1] = (bf16)e1;
            P_lds[buf][wv][g * 4 + r][c] = pk;  // keys 2c,2c+1 adjacent
        }
        // same-wave DS ordering: read sees this wave's writes, no barrier
        bf16x8 ap = *(const bf16x8*)&P_lds[buf][wv][c][g * 4];
        o0 = __builtin_amdgcn_mfma_f32_16x16x32_bf16(ap, cva, o0, 0, 0, 0);
        o1 = __builtin_amdgcn_mfma_f32_16x16x32_bf16(ap, cvb, o1, 0, 0, 0);
    }
    // reduce l across the 16 lanes sharing g (keys split over lane&15)
#pragma unroll
    for (int r = 0; r < 4; r++) {
        float s = l[r];
        s += __shfl_xor(s, 1);
        s += __shfl_xor(s, 2);
        s += __shfl_xor(s, 4);
        s += __shfl_xor(s, 8);
        l[r] = 1.0f / s;
    }
    int h = sh & 3, sb = sh >> 2;
#pragma unroll
    for (int r = 0; r < 4; r++) {
        size_t row = (size_t)sb * Lq + q0 + g * 4 + r;
        ATTh[row * 128 + h * 32 + c] = (bf16)(o0[r] * l[r]);
        ATTh[row * 128 + h * 32 + 16 + c] = (bf16)(o1[r] * l[r]);
    }
}

// ---------------------------------------------------------------------------
// Residual + LN: y = LN(xin + delta)*g + be. Writes fp32 (if xf) and bf16
// (if xh, with row stride hstride — used to write into the CAT buffer).
__global__ void k_ln_res(const float* __restrict__ xin, const float* __restrict__ delta,
                         const float* __restrict__ g, const float* __restrict__ be,
                         float* __restrict__ xf, bf16* __restrict__ xh, int hstride) {
    int tok = blockIdx.x;
    int d = threadIdx.x;
    __shared__ float scratch[128];
    float v = xin[(size_t)tok * 128 + d] + delta[(size_t)tok * 128 + d];
    float mean = block_sum(v, scratch) * (1.0f / 128.0f);
    float dv = v - mean;
    float var = block_sum(dv * dv, scratch) * (1.0f / 128.0f);
    float y = dv * rsqrtf(var + 1e-5f) * g[d] + be[d];
    if (xf) xf[(size_t)tok * 128 + d] = y;
    if (xh) xh[(size_t)tok * hstride + d] = (bf16)y;
}

// Fill CAT[:,128:256] from encoder output X0h (xt order -> (b,t,n) order).
__global__ void k_cat(const bf16* __restrict__ X0h, bf16* __restrict__ CATh) {
    int i = blockIdx.x * 256 + threadIdx.x;   // over 1048576
    if (i >= 1048576) return;
    int tok = i >> 7, d = i & 127;
    int b = tok >> 11, t = (tok >> 3) & 255, n = tok & 7;
    CATh[(size_t)tok * 256 + 128 + d] = X0h[((size_t)(b * 8 + n) * 256 + t) * 128 + d];
}

// ---------------------------------------------------------------------------
extern "C" void kernel_launch(void* const* d_in, const int* in_sizes, int n_in,
                              void* d_out, int out_size, void* d_ws, size_t ws_size,
                              hipStream_t stream) {
    const float* vs       = (const float*)d_in[0];
    const float* semb     = (const float*)d_in[1];
    const float* r5       = (const float*)d_in[2];
    const float* A55      = (const float*)d_in[3];
    const float* bl_bias  = (const float*)d_in[4];
    const float* nl_W1    = (const float*)d_in[5];
    const float* nl_b1    = (const float*)d_in[6];
    const float* nl_W2    = (const float*)d_in[7];
    const float* nl_b2    = (const float*)d_in[8];
    const float* mlp_W1   = (const float*)d_in[9];
    const float* mlp_b1   = (const float*)d_in[10];
    const float* mlp_W2   = (const float*)d_in[11];
    const float* mlp_b2   = (const float*)d_in[12];
    const float* mlp_ln_g = (const float*)d_in[13];
    const float* mlp_ln_b = (const float*)d_in[14];
    const float* enc_qkv_W = (const float*)d_in[15];
    const float* enc_qkv_b = (const float*)d_in[16];
    const float* enc_out_W = (const float*)d_in[17];
    const float* enc_out_b = (const float*)d_in[18];
    const float* enc_ln1_g = (const float*)d_in[19];
    const float* enc_ln1_b = (const float*)d_in[20];
    const float* enc_ff_W1 = (const float*)d_in[21];
    const float* enc_ff_b1 = (const float*)d_in[22];
    const float* enc_ff_W2 = (const float*)d_in[23];
    const float* enc_ff_b2 = (const float*)d_in[24];
    const float* enc_ln2_g = (const float*)d_in[25];
    const float* enc_ln2_b = (const float*)d_in[26];
    const float* ca_Wq = (const float*)d_in[27];
    const float* ca_bq = (const float*)d_in[28];
    const float* ca_Wk = (const float*)d_in[29];
    const float* ca_bk = (const float*)d_in[30];
    const float* ca_Wv = (const float*)d_in[31];
    const float* ca_bv = (const float*)d_in[32];
    const float* ca_Wo = (const float*)d_in[33];
    const float* ca_bo = (const float*)d_in[34];
    const float* ca_ln1_g = (const float*)d_in[35];
    const float* ca_ln1_b = (const float*)d_in[36];
    const float* ca_ff_W1 = (const float*)d_in[37];
    const float* ca_ff_b1 = (const float*)d_in[38];
    const float* ca_ff_W2 = (const float*)d_in[39];
    const float* ca_ff_b2 = (const float*)d_in[40];
    const float* ca_ln2_g = (const float*)d_in[41];
    const float* ca_ln2_b = (const float*)d_in[42];
    float* out = (float*)d_out;

    // Workspace layout (byte offsets, 256-aligned)
    char* base = (char*)d_ws;
    float* b1w   = (float*)(base + 0);          //  32 KB
    float* resid = (float*)(base + 32768);      // 128 KB
    float* X0    = (float*)(base + 163840);     //   4 MB
    float* X1    = (float*)(base + 4358144);    //   4 MB
    char*  QKVr  = base + 8552448;              //  12 MB region
    float* OF    = (float*)(base + 21135360);   //   4 MB
    bf16*  Wpk   = (bf16*) (base + 25329664);   // 1.03 MB
    float* bpk   = (float*)(base + 26411008);   //   1 KB
    bf16*  X0h   = (bf16*) (base + 26412032);   //   2 MB
    bf16*  X1h   = (bf16*) (base + 28509184);   //   2 MB
    bf16*  sembh = (bf16*) (base + 30606336);   //   2 MB
    bf16*  ATTh  = (bf16*) (base + 32703488);   //   2 MB
    bf16*  Qh    = (bf16*)QKVr;                 //   2 MB
    bf16*  Kh    = (bf16*)(QKVr + 2097152);     //   2 MB
    bf16*  Vth   = (bf16*)(QKVr + 4194304);     //   2 MB
    bf16*  CATh  = (bf16*)QKVr;                 //   4 MB (after attn done)
    bf16*  Hh    = (bf16*)(QKVr + 4194304);     //  <=8 MB (after attn done)

    const int NTOK = B_ * T_ * N_;  // 8192

    // Prep (weights + semb cast + bias pack), one launch
    k_prep<<<dim3(6209), dim3(256), 0, stream>>>(
        enc_qkv_W, enc_out_W, enc_ff_W1, enc_ff_W2, ca_Wq, ca_Wk, ca_Wv, ca_Wo,
        ca_ff_W1, ca_ff_W2, mlp_W2, semb, ca_bk, ca_bv, Wpk, sembh, bpk);

    // Residual features + token MLP
    k_b1<<<dim3((B_ * (T_ - 1) + 63) / 64), dim3(64), 0, stream>>>(
        vs, r5, A55, bl_bias, nl_W1, nl_b1, nl_W2, nl_b2, b1w);
    k_resid<<<dim3(NTOK / 64), dim3(64), 0, stream>>>(vs, b1w, resid);
    k_mlp1<<<dim3(NTOK), dim3(128), 0, stream>>>(resid, mlp_W1, mlp_b1, (bf16*)X1h);
    k_gemm<<<dim3(1024), dim3(256), 0, stream>>>(
        (bf16*)X1h, Wpk + 524288, mlp_b2, OF, nullptr, nullptr, nullptr, nullptr,
        NTOK, 128, 128, 0, 0);
    k_mlp2<<<dim3(NTOK), dim3(128), 0, stream>>>(OF, mlp_ln_g, mlp_ln_b, X0, X0h);

    // Encoder layers
    for (int i = 0; i < LENC_; i++) {
        k_gemm<<<dim3(3072), dim3(256), 0, stream>>>(
            X0h, Wpk + i * 49152, enc_qkv_b + i * 384, nullptr, nullptr,
            Qh, Kh, Vth, NTOK, 384, 128, 0, 1);
        k_mattn<<<dim3(128 * 4), dim3(256), 0, stream>>>(Qh, Kh, Vth, ATTh, 256, 256);
        k_gemm<<<dim3(1024), dim3(256), 0, stream>>>(
            ATTh, Wpk + 98304 + i * 16384, enc_out_b + i * 128, OF, nullptr,
            nullptr, nullptr, nullptr, NTOK, 128, 128, 0, 0);
        k_ln_res<<<dim3(NTOK), dim3(128), 0, stream>>>(
            X0, OF, enc_ln1_g + i * 128, enc_ln1_b + i * 128, X1, X1h, 128);
        k_gemm<<<dim3(2048), dim3(256), 0, stream>>>(
            X1h, Wpk + 131072 + i * 32768, enc_ff_b1 + i * 256, nullptr, Hh,
            nullptr, nullptr, nullptr, NTOK, 256, 128, 1, 0);
        k_gemm<<<dim3(1024), dim3(256), 0, stream>>>(
            Hh, Wpk + 196608 + i * 32768, enc_ff_b2 + i * 128, OF, nullptr,
            nullptr, nullptr, nullptr, NTOK, 128, 256, 0, 0);
        k_ln_res<<<dim3(NTOK), dim3(128), 0, stream>>>(
            X1, OF, enc_ln2_g + i * 128, enc_ln2_b + i * 128, X0, X0h, 128);
    }

    // Cross-attention (NSH = 16, Lq = Lk = 2048)
    k_gemm<<<dim3(1024), dim3(256), 0, stream>>>(
        sembh, Wpk + 262144, ca_bq, nullptr, nullptr, Qh, nullptr, nullptr,
        NTOK, 128, 128, 0, 2);
    k_gemm<<<dim3(2048), dim3(256), 0, stream>>>(
        X0h, Wpk + 278528, bpk, nullptr, nullptr, nullptr, Kh, Vth,
        NTOK, 256, 128, 0, 3);
    k_mattn<<<dim3(16 * 32), dim3(256), 0, stream>>>(Qh, Kh, Vth, ATTh, 2048, 2048);
    k_gemm<<<dim3(1024), dim3(256), 0, stream>>>(
        ATTh, Wpk + 311296, ca_bo, OF, nullptr, nullptr, nullptr, nullptr,
        NTOK, 128, 128, 0, 0);
    k_ln_res<<<dim3(NTOK), dim3(128), 0, stream>>>(
        semb, OF, ca_ln1_g, ca_ln1_b, X1, CATh, 256);  // X1 = s1; CAT[:, :128]
    k_cat<<<dim3(4096), dim3(256), 0, stream>>>(X0h, CATh);
    k_gemm<<<dim3(4096), dim3(256), 0, stream>>>(
        CATh, Wpk + 327680, ca_ff_b1, nullptr, Hh, nullptr, nullptr, nullptr,
        NTOK, 512, 256, 1, 0);
    k_gemm<<<dim3(1024), dim3(256), 0, stream>>>(
        Hh, Wpk + 458752, ca_ff_b2, OF, nullptr, nullptr, nullptr, nullptr,
        NTOK, 128, 512, 0, 0);
    k_ln_res<<<dim3(NTOK), dim3(128), 0, stream>>>(
        X1, OF, ca_ln2_g, ca_ln2_b, out, nullptr, 128);
}